// Round 1
// baseline (3493.196 us; speedup 1.0000x reference)
//
#include <hip/hip_runtime.h>
#include <cstddef>
#include <cstdint>

#define BM 128
#define BN 128
#define BK 16
#define PAD 4

// C[M,N] = op(A) @ B.  op=N: A is [M,K] row-major.  op=T: A is [K,M] row-major.
// B is [K,N] row-major, C row-major. All dims multiples of tile sizes (guaranteed here).
template<bool TRANS_A>
__global__ __launch_bounds__(256)
void sgemm_kernel(const float* __restrict__ A, const float* __restrict__ B,
                  float* __restrict__ C, int M, int N, int K)
{
    __shared__ float As[BK][BM + PAD];   // k-major: As[k][m]
    __shared__ float Bs[BK][BN + PAD];   // k-major: Bs[k][n]

    const int tid = threadIdx.x;
    const int tx = tid & 15;     // 16 threads across n
    const int ty = tid >> 4;     // 16 threads across m
    const int n0 = blockIdx.x * BN;
    const int m0 = blockIdx.y * BM;

    float acc[8][8] __attribute__((aligned(16)));
    #pragma unroll
    for (int i = 0; i < 8; ++i)
        #pragma unroll
        for (int j = 0; j < 8; ++j) acc[i][j] = 0.0f;

    for (int kt = 0; kt < K; kt += BK) {
        // ---- load B tile: BK x BN = 512 float4, 2 per thread ----
        #pragma unroll
        for (int it = 0; it < 2; ++it) {
            int f = tid + it * 256;
            int kb = f >> 5, nb = f & 31;
            *(float4*)&Bs[kb][nb * 4] =
                *(const float4*)&B[(size_t)(kt + kb) * N + n0 + nb * 4];
        }
        // ---- load A tile ----
        if (TRANS_A) {
            // op(A)[m,k] = A[k,m]: m is contiguous -> direct vector copy
            #pragma unroll
            for (int it = 0; it < 2; ++it) {
                int f = tid + it * 256;
                int ka = f >> 5, ma = f & 31;
                *(float4*)&As[ka][ma * 4] =
                    *(const float4*)&A[(size_t)(kt + ka) * M + m0 + ma * 4];
            }
        } else {
            // A[m,k]: vector load along k, scatter-transpose into As[k][m]
            #pragma unroll
            for (int it = 0; it < 2; ++it) {
                int f = tid + it * 256;
                int m = f >> 2, k4 = f & 3;
                float4 v = *(const float4*)&A[(size_t)(m0 + m) * K + kt + k4 * 4];
                As[k4 * 4 + 0][m] = v.x;
                As[k4 * 4 + 1][m] = v.y;
                As[k4 * 4 + 2][m] = v.z;
                As[k4 * 4 + 3][m] = v.w;
            }
        }
        __syncthreads();

        // ---- compute: 8x8 microtile, split 4+4 to keep LDS reads 2-way max ----
        #pragma unroll
        for (int k = 0; k < BK; ++k) {
            float a[8] __attribute__((aligned(16)));
            float b[8] __attribute__((aligned(16)));
            *(float4*)&a[0] = *(float4*)&As[k][ty * 4];
            *(float4*)&a[4] = *(float4*)&As[k][64 + ty * 4];
            *(float4*)&b[0] = *(float4*)&Bs[k][tx * 4];
            *(float4*)&b[4] = *(float4*)&Bs[k][64 + tx * 4];
            #pragma unroll
            for (int i = 0; i < 8; ++i)
                #pragma unroll
                for (int j = 0; j < 8; ++j)
                    acc[i][j] = fmaf(a[i], b[j], acc[i][j]);
        }
        __syncthreads();
    }

    // ---- store: rows ty*4+{0..3} and 64+ty*4+{0..3}; col groups tx*4, 64+tx*4 ----
    #pragma unroll
    for (int i = 0; i < 8; ++i) {
        int gm = m0 + ((i < 4) ? (ty * 4 + i) : (64 + ty * 4 + (i - 4)));
        float* crow = C + (size_t)gm * N + n0;
        *(float4*)&crow[tx * 4]      = *(float4*)&acc[i][0];
        *(float4*)&crow[64 + tx * 4] = *(float4*)&acc[i][4];
    }
}

// In-place row softmax over 2048 columns. One 256-thread block per row.
__global__ __launch_bounds__(256)
void softmax_rows_kernel(float* __restrict__ S)
{
    const int row = blockIdx.x;
    float* p = S + (size_t)row * 2048;
    const int tid = threadIdx.x;

    float4 v0 = *(float4*)&p[tid * 4];
    float4 v1 = *(float4*)&p[1024 + tid * 4];

    float m = fmaxf(fmaxf(fmaxf(v0.x, v0.y), fmaxf(v0.z, v0.w)),
                    fmaxf(fmaxf(v1.x, v1.y), fmaxf(v1.z, v1.w)));
    #pragma unroll
    for (int off = 32; off > 0; off >>= 1)
        m = fmaxf(m, __shfl_xor(m, off, 64));
    __shared__ float redm[4];
    if ((tid & 63) == 0) redm[tid >> 6] = m;
    __syncthreads();
    m = fmaxf(fmaxf(redm[0], redm[1]), fmaxf(redm[2], redm[3]));

    v0.x = __expf(v0.x - m); v0.y = __expf(v0.y - m);
    v0.z = __expf(v0.z - m); v0.w = __expf(v0.w - m);
    v1.x = __expf(v1.x - m); v1.y = __expf(v1.y - m);
    v1.z = __expf(v1.z - m); v1.w = __expf(v1.w - m);

    float s = v0.x + v0.y + v0.z + v0.w + v1.x + v1.y + v1.z + v1.w;
    #pragma unroll
    for (int off = 32; off > 0; off >>= 1)
        s += __shfl_xor(s, off, 64);
    __shared__ float reds[4];
    if ((tid & 63) == 0) reds[tid >> 6] = s;
    __syncthreads();
    s = reds[0] + reds[1] + reds[2] + reds[3];

    const float r = 1.0f / s;
    v0.x *= r; v0.y *= r; v0.z *= r; v0.w *= r;
    v1.x *= r; v1.y *= r; v1.z *= r; v1.w *= r;

    *(float4*)&p[tid * 4]        = v0;
    *(float4*)&p[1024 + tid * 4] = v1;
}

extern "C" void kernel_launch(void* const* d_in, const int* in_sizes, int n_in,
                              void* d_out, int out_size, void* d_ws, size_t ws_size,
                              hipStream_t stream)
{
    const int B = 4, D = 1024, N = 2048, MH = 1024, MV = 1024;
    const float* x   = (const float*)d_in[0];
    const float* W_Q = (const float*)d_in[1];
    const float* W_K = (const float*)d_in[2];
    const float* W_V = (const float*)d_in[3];
    const float* W_O = (const float*)d_in[4];
    float* out = (float*)d_out;

    // Per-batch workspace (reused across batches): 48 MB total.
    char* ws = (char*)d_ws;
    float* Qb = (float*)(ws);
    float* Kb = (float*)(ws + (size_t)8  * 1024 * 1024);
    float* Vb = (float*)(ws + (size_t)16 * 1024 * 1024);
    float* Sb = (float*)(ws + (size_t)24 * 1024 * 1024);  // 16 MB
    float* Ab = (float*)(ws + (size_t)40 * 1024 * 1024);

    dim3 blk(256);
    dim3 gProj(N / BN, MH / BM);   // (16, 8)
    dim3 gScore(N / BN, N / BM);   // (16, 16)

    for (int b = 0; b < B; ++b) {
        const float* xb = x + (size_t)b * D * N;
        float* outb = out + (size_t)b * D * N;

        // Q = W_Q @ x_b ; K = W_K @ x_b ; V = W_V @ x_b   (each [1024, 2048])
        hipLaunchKernelGGL((sgemm_kernel<false>), gProj, blk, 0, stream, W_Q, xb, Qb, MH, N, D);
        hipLaunchKernelGGL((sgemm_kernel<false>), gProj, blk, 0, stream, W_K, xb, Kb, MH, N, D);
        hipLaunchKernelGGL((sgemm_kernel<false>), gProj, blk, 0, stream, W_V, xb, Vb, MV, N, D);

        // S[i,j] = sum_h K[h,i] * Q[h,j]  -> K^T @ Q  [2048, 2048]
        hipLaunchKernelGGL((sgemm_kernel<true>), gScore, blk, 0, stream, Kb, Qb, Sb, N, N, MH);

        // row-wise softmax (axis j)
        hipLaunchKernelGGL(softmax_rows_kernel, dim3(N), blk, 0, stream, Sb);

        // attn = V @ P  [1024, 2048]
        hipLaunchKernelGGL((sgemm_kernel<false>), gProj, blk, 0, stream, Vb, Sb, Ab, MV, N, N);

        // out_b = W_O @ attn  [1024, 2048]
        hipLaunchKernelGGL((sgemm_kernel<false>), gProj, blk, 0, stream, W_O, Ab, outb, D, N, MV);
    }
}

// Round 2
// 589.888 us; speedup vs baseline: 5.9218x; 5.9218x over previous
//
#include <hip/hip_runtime.h>
#include <cstddef>
#include <cstdint>

typedef unsigned short u16;
typedef __attribute__((ext_vector_type(8))) short bf16x8;
typedef __attribute__((ext_vector_type(4))) float f32x4;

#define GLOBAL_AS __attribute__((address_space(1)))
#define LDS_AS __attribute__((address_space(3)))

__device__ __forceinline__ void async16(const u16* g, u16* l) {
    __builtin_amdgcn_global_load_lds((GLOBAL_AS const uint32_t*)g,
                                     (LDS_AS uint32_t*)l, 16, 0, 0);
}

__device__ __forceinline__ u16 f2bf(float f) {
    uint32_t u = __builtin_bit_cast(uint32_t, f);
    uint32_t r = (u + 0x7FFFu + ((u >> 16) & 1u)) >> 16;
    return (u16)r;
}
__device__ __forceinline__ float bf2f(u16 u) {
    return __builtin_bit_cast(float, (uint32_t)u << 16);
}

// ---------------- weight prep ----------------
// fp32 -> 3 bf16 planes (same layout). n4 = count/4 handled exactly by grid.
__global__ __launch_bounds__(256)
void wsplit3(const float4* __restrict__ src, u16* __restrict__ dst, size_t plane)
{
    int i = blockIdx.x * 256 + threadIdx.x;
    float4 v = src[i];
    u16 a0[4], a1[4], a2[4];
    float c[4] = {v.x, v.y, v.z, v.w};
    #pragma unroll
    for (int k = 0; k < 4; ++k) {
        u16 u0 = f2bf(c[k]);
        float r1 = c[k] - bf2f(u0);
        u16 u1 = f2bf(r1);
        float r2 = r1 - bf2f(u1);
        u16 u2 = f2bf(r2);
        a0[k] = u0; a1[k] = u1; a2[k] = u2;
    }
    *(ushort4*)&dst[4 * (size_t)i]             = *(ushort4*)a0;
    *(ushort4*)&dst[plane + 4 * (size_t)i]     = *(ushort4*)a1;
    *(ushort4*)&dst[2 * plane + 4 * (size_t)i] = *(ushort4*)a2;
}

__global__ __launch_bounds__(256)
void wcast(const float4* __restrict__ src, u16* __restrict__ dst)
{
    int i = blockIdx.x * 256 + threadIdx.x;
    float4 v = src[i];
    ushort4 a = { f2bf(v.x), f2bf(v.y), f2bf(v.z), f2bf(v.w) };
    *(ushort4*)&dst[4 * (size_t)i] = a;
}

// ---------------- transpose + 3-split ----------------
// src fp32 [1024, 2048] -> dst 3 bf16 planes [2048, 1024]
__global__ __launch_bounds__(256)
void tsplit3(const float* __restrict__ Sb, size_t sBatch,
             u16* __restrict__ Db, size_t dBatch, size_t plane)
{
    const float* S = Sb + blockIdx.z * sBatch;
    u16* D = Db + blockIdx.z * dBatch;
    __shared__ float t[32][33];
    int tx = threadIdx.x & 31, ty = threadIdx.x >> 5;
    int c0 = blockIdx.x * 32, r0 = blockIdx.y * 32;
    #pragma unroll
    for (int k = 0; k < 4; ++k)
        t[ty + 8 * k][tx] = S[(size_t)(r0 + ty + 8 * k) * 2048 + c0 + tx];
    __syncthreads();
    #pragma unroll
    for (int k = 0; k < 4; ++k) {
        float a = t[tx][ty + 8 * k];
        u16 u0 = f2bf(a);
        float r1 = a - bf2f(u0);
        u16 u1 = f2bf(r1);
        float r2 = r1 - bf2f(u1);
        u16 u2 = f2bf(r2);
        size_t o = (size_t)(c0 + ty + 8 * k) * 1024 + r0 + tx;
        D[o] = u0; D[plane + o] = u1; D[2 * plane + o] = u2;
    }
}

// bf16 [2048,2048] transpose
__global__ __launch_bounds__(256)
void tbf16(const u16* __restrict__ Sb, size_t sBatch, u16* __restrict__ Db, size_t dBatch)
{
    const u16* S = Sb + blockIdx.z * sBatch;
    u16* D = Db + blockIdx.z * dBatch;
    __shared__ u16 t[32][34];
    int tx = threadIdx.x & 31, ty = threadIdx.x >> 5;
    int c0 = blockIdx.x * 32, r0 = blockIdx.y * 32;
    #pragma unroll
    for (int k = 0; k < 4; ++k)
        t[ty + 8 * k][tx] = S[(size_t)(r0 + ty + 8 * k) * 2048 + c0 + tx];
    __syncthreads();
    #pragma unroll
    for (int k = 0; k < 4; ++k)
        D[(size_t)(c0 + ty + 8 * k) * 2048 + r0 + tx] = t[tx][ty + 8 * k];
}

// ---------------- split-3 six-term MFMA GEMM ----------------
// C[M,N] fp32 = sum over 6 plane-pairs of A_pa[M,K] * B_pb[N,K]^T  (both k-contiguous)
__global__ __launch_bounds__(256)
void gemm_s3(const u16* __restrict__ Ab, size_t aBatch, size_t aPlane,
             const u16* __restrict__ Bb, size_t bBatch, size_t bPlane,
             float* __restrict__ Cb, size_t cBatch,
             int M, int N, int K)
{
    __shared__ u16 lds[6][4096];   // A0,A1,A2,B0,B1,B2 tiles: 128 rows x 32 bf16
    const u16* A = Ab + blockIdx.z * aBatch;
    const u16* B = Bb + blockIdx.z * bBatch;
    float* C = Cb + blockIdx.z * cBatch;
    const int tid = threadIdx.x;
    const int lane = tid & 63, wave = tid >> 6;
    const int m0 = blockIdx.y * 128, n0 = blockIdx.x * 128;
    const int l15 = lane & 15, q = lane >> 4;
    const int rm = (wave >> 1) * 64, rn = (wave & 1) * 64;

    // staging: slot s = tid + it*256 -> row s>>2, phys group s&3 holds logical (s&3)^f(row), f(r)=(r>>1)&3
    int sr[2], sg[2];
    #pragma unroll
    for (int it = 0; it < 2; ++it) {
        int s = tid + it * 256;
        sr[it] = s >> 2;
        sg[it] = (s & 3) ^ ((sr[it] >> 1) & 3);
    }
    // fragment LDS offsets (ushort units), phys group = q ^ f(m), f(m)=(l15>>1)&3
    const int fsw = q ^ ((l15 >> 1) & 3);
    int aoff[4], boff[4];
    #pragma unroll
    for (int f = 0; f < 4; ++f) {
        aoff[f] = (rm + f * 16 + l15) * 32 + fsw * 8;
        boff[f] = (rn + f * 16 + l15) * 32 + fsw * 8;
    }

    f32x4 acc[4][4];
    #pragma unroll
    for (int i = 0; i < 4; ++i)
        #pragma unroll
        for (int j = 0; j < 4; ++j)
            acc[i][j] = (f32x4){0.f, 0.f, 0.f, 0.f};

    for (int kt = 0; kt < K; kt += 32) {
        #pragma unroll
        for (int p = 0; p < 3; ++p) {
            #pragma unroll
            for (int it = 0; it < 2; ++it) {
                async16(A + p * aPlane + (size_t)(m0 + sr[it]) * K + kt + sg[it] * 8,
                        &lds[p][(it * 256 + wave * 64) * 8]);
                async16(B + p * bPlane + (size_t)(n0 + sr[it]) * K + kt + sg[it] * 8,
                        &lds[3 + p][(it * 256 + wave * 64) * 8]);
            }
        }
        __syncthreads();
        const int PA[6] = {0, 0, 1, 1, 0, 2};
        const int PB[6] = {0, 1, 0, 1, 2, 0};
        #pragma unroll
        for (int t = 0; t < 6; ++t) {
            bf16x8 af[4], bfr[4];
            #pragma unroll
            for (int f = 0; f < 4; ++f) af[f] = *(const bf16x8*)&lds[PA[t]][aoff[f]];
            #pragma unroll
            for (int f = 0; f < 4; ++f) bfr[f] = *(const bf16x8*)&lds[3 + PB[t]][boff[f]];
            #pragma unroll
            for (int i = 0; i < 4; ++i)
                #pragma unroll
                for (int j = 0; j < 4; ++j)
                    acc[i][j] = __builtin_amdgcn_mfma_f32_16x16x32_bf16(af[i], bfr[j], acc[i][j], 0, 0, 0);
        }
        __syncthreads();
    }

    #pragma unroll
    for (int i = 0; i < 4; ++i) {
        int row = m0 + rm + i * 16 + q * 4;
        #pragma unroll
        for (int j = 0; j < 4; ++j) {
            int col = n0 + rn + j * 16 + l15;
            #pragma unroll
            for (int r = 0; r < 4; ++r)
                C[(size_t)(row + r) * N + col] = acc[i][j][r];
        }
    }
}

// ---------------- plain bf16 MFMA GEMM (NT) ----------------
template<bool BF16OUT>
__global__ __launch_bounds__(256)
void gemm_nt(const u16* __restrict__ Ab, size_t aBatch,
             const u16* __restrict__ Bb, size_t bBatch,
             void* __restrict__ Cb, size_t cBatch,
             int M, int N, int K)
{
    __shared__ u16 lds[2][8192];   // 128 rows x 64 bf16 each
    const u16* A = Ab + blockIdx.z * aBatch;
    const u16* B = Bb + blockIdx.z * bBatch;
    const int tid = threadIdx.x;
    const int lane = tid & 63, wave = tid >> 6;
    const int m0 = blockIdx.y * 128, n0 = blockIdx.x * 128;
    const int l15 = lane & 15, q = lane >> 4;
    const int rm = (wave >> 1) * 64, rn = (wave & 1) * 64;

    int sr[4], sg[4];
    #pragma unroll
    for (int it = 0; it < 4; ++it) {
        int s = tid + it * 256;
        sr[it] = s >> 3;
        sg[it] = (s & 7) ^ (sr[it] & 7);
    }
    const int fsw = l15 & 7;
    int aoff[4], boff[4];
    #pragma unroll
    for (int f = 0; f < 4; ++f) {
        aoff[f] = (rm + f * 16 + l15) * 64;
        boff[f] = (rn + f * 16 + l15) * 64;
    }

    f32x4 acc[4][4];
    #pragma unroll
    for (int i = 0; i < 4; ++i)
        #pragma unroll
        for (int j = 0; j < 4; ++j)
            acc[i][j] = (f32x4){0.f, 0.f, 0.f, 0.f};

    for (int kt = 0; kt < K; kt += 64) {
        #pragma unroll
        for (int it = 0; it < 4; ++it) {
            async16(A + (size_t)(m0 + sr[it]) * K + kt + sg[it] * 8,
                    &lds[0][(it * 256 + wave * 64) * 8]);
            async16(B + (size_t)(n0 + sr[it]) * K + kt + sg[it] * 8,
                    &lds[1][(it * 256 + wave * 64) * 8]);
        }
        __syncthreads();
        #pragma unroll
        for (int c = 0; c < 2; ++c) {
            int ga = ((c * 4 + q) ^ fsw) * 8;
            bf16x8 af[4], bfr[4];
            #pragma unroll
            for (int f = 0; f < 4; ++f) af[f] = *(const bf16x8*)&lds[0][aoff[f] + ga];
            #pragma unroll
            for (int f = 0; f < 4; ++f) bfr[f] = *(const bf16x8*)&lds[1][boff[f] + ga];
            #pragma unroll
            for (int i = 0; i < 4; ++i)
                #pragma unroll
                for (int j = 0; j < 4; ++j)
                    acc[i][j] = __builtin_amdgcn_mfma_f32_16x16x32_bf16(af[i], bfr[j], acc[i][j], 0, 0, 0);
        }
        __syncthreads();
    }

    #pragma unroll
    for (int i = 0; i < 4; ++i) {
        int row = m0 + rm + i * 16 + q * 4;
        #pragma unroll
        for (int j = 0; j < 4; ++j) {
            int col = n0 + rn + j * 16 + l15;
            if (BF16OUT) {
                u16* Co = (u16*)Cb + blockIdx.z * cBatch;
                #pragma unroll
                for (int r = 0; r < 4; ++r)
                    Co[(size_t)(row + r) * N + col] = f2bf(acc[i][j][r]);
            } else {
                float* Co = (float*)Cb + blockIdx.z * cBatch;
                #pragma unroll
                for (int r = 0; r < 4; ++r)
                    Co[(size_t)(row + r) * N + col] = acc[i][j][r];
            }
        }
    }
}

// ---------------- row softmax -> bf16 P ----------------
__global__ __launch_bounds__(256)
void softmax_p(const float* __restrict__ Sb, size_t sBatch, u16* __restrict__ Pb, size_t pBatch)
{
    const float* S = Sb + blockIdx.y * sBatch + (size_t)blockIdx.x * 2048;
    u16* P = Pb + blockIdx.y * pBatch + (size_t)blockIdx.x * 2048;
    const int tid = threadIdx.x;

    float4 v0 = *(const float4*)&S[tid * 4];
    float4 v1 = *(const float4*)&S[1024 + tid * 4];

    float m = fmaxf(fmaxf(fmaxf(v0.x, v0.y), fmaxf(v0.z, v0.w)),
                    fmaxf(fmaxf(v1.x, v1.y), fmaxf(v1.z, v1.w)));
    #pragma unroll
    for (int off = 32; off > 0; off >>= 1)
        m = fmaxf(m, __shfl_xor(m, off, 64));
    __shared__ float redm[4];
    if ((tid & 63) == 0) redm[tid >> 6] = m;
    __syncthreads();
    m = fmaxf(fmaxf(redm[0], redm[1]), fmaxf(redm[2], redm[3]));

    v0.x = __expf(v0.x - m); v0.y = __expf(v0.y - m);
    v0.z = __expf(v0.z - m); v0.w = __expf(v0.w - m);
    v1.x = __expf(v1.x - m); v1.y = __expf(v1.y - m);
    v1.z = __expf(v1.z - m); v1.w = __expf(v1.w - m);

    float s = v0.x + v0.y + v0.z + v0.w + v1.x + v1.y + v1.z + v1.w;
    #pragma unroll
    for (int off = 32; off > 0; off >>= 1)
        s += __shfl_xor(s, off, 64);
    __shared__ float reds[4];
    if ((tid & 63) == 0) reds[tid >> 6] = s;
    __syncthreads();
    s = reds[0] + reds[1] + reds[2] + reds[3];

    const float r = 1.0f / s;
    ushort4 o0 = { f2bf(v0.x * r), f2bf(v0.y * r), f2bf(v0.z * r), f2bf(v0.w * r) };
    ushort4 o1 = { f2bf(v1.x * r), f2bf(v1.y * r), f2bf(v1.z * r), f2bf(v1.w * r) };
    *(ushort4*)&P[tid * 4] = o0;
    *(ushort4*)&P[1024 + tid * 4] = o1;
}

// ---------------- driver ----------------
extern "C" void kernel_launch(void* const* d_in, const int* in_sizes, int n_in,
                              void* d_out, int out_size, void* d_ws, size_t ws_size,
                              hipStream_t stream)
{
    const size_t WREG = 16777216;      // weight region bytes
    const size_t PER  = 46137344;      // per-batch region bytes
    const size_t P_US = PER / 2, P_F = PER / 4;

    char* ws = (char*)d_ws;
    u16* WQ3 = (u16*)ws;                      // 3 planes, plane stride 1048576 us
    u16* WK3 = (u16*)(ws + 6291456);
    u16* WVb = (u16*)(ws + 12582912);
    u16* WOb = (u16*)(ws + 14680064);

    int G = (ws_size >= WREG + 4 * PER) ? 4 : (ws_size >= WREG + 2 * PER) ? 2 : 1;

    const float* x = (const float*)d_in[0];
    float* out = (float*)d_out;
    dim3 blk(256);

    // weights: once per launch
    wsplit3<<<1024, blk, 0, stream>>>((const float4*)d_in[1], WQ3, 1048576);
    wsplit3<<<1024, blk, 0, stream>>>((const float4*)d_in[2], WK3, 1048576);
    wcast  <<<1024, blk, 0, stream>>>((const float4*)d_in[3], WVb);
    wcast  <<<1024, blk, 0, stream>>>((const float4*)d_in[4], WOb);

    for (int b0 = 0; b0 < 4; b0 += G) {
        char* R = ws + WREG + (size_t)b0 * PER;
        u16*   xT3 = (u16*)R;                       // later QT3, then P
        float* Q32 = (float*)(R + 12582912);
        float* K32 = (float*)(R + 20971520);
        float* S32 = (float*)(R + 12582912);        // over Q32/K32 (dead)
        u16*   KT3 = (u16*)(R + 29360128);          // later PT
        u16*   Vb  = (u16*)(R + 41943040);
        u16*   Pb  = (u16*)R;
        u16*   PTb = (u16*)(R + 29360128);
        u16*   ATb = (u16*)(R + 12582912);          // over S (dead)

        // x -> xT3 (3 bf16 planes, [n, d])
        tsplit3<<<dim3(64, 32, G), blk, 0, stream>>>(x + (size_t)b0 * 2097152, 2097152,
                                                     xT3, P_US, 2097152);
        // Q = W_Q x, K = W_K x  (6-term split)
        gemm_s3<<<dim3(16, 8, G), blk, 0, stream>>>(WQ3, 0, 1048576, xT3, P_US, 2097152,
                                                    Q32, P_F, 1024, 2048, 1024);
        gemm_s3<<<dim3(16, 8, G), blk, 0, stream>>>(WK3, 0, 1048576, xT3, P_US, 2097152,
                                                    K32, P_F, 1024, 2048, 1024);
        // V = W_V x (plain bf16; B = xT3 plane 0) -> bf16 V [v, i]
        gemm_nt<true><<<dim3(16, 8, G), blk, 0, stream>>>(WVb, 0, xT3, P_US,
                                                          Vb, P_US, 1024, 2048, 1024);
        // Q,K -> transposed 3-plane splits
        tsplit3<<<dim3(64, 32, G), blk, 0, stream>>>(Q32, P_F, xT3 /*QT3*/, P_US, 2097152);
        tsplit3<<<dim3(64, 32, G), blk, 0, stream>>>(K32, P_F, KT3, P_US, 2097152);
        // S[i,j] = K^T Q  (6-term split)
        gemm_s3<<<dim3(16, 16, G), blk, 0, stream>>>(KT3, P_US, 2097152, xT3 /*QT3*/, P_US, 2097152,
                                                     S32, P_F, 2048, 2048, 1024);
        // softmax rows -> P bf16
        softmax_p<<<dim3(2048, G), blk, 0, stream>>>(S32, P_F, Pb, P_US);
        // P -> PT
        tbf16<<<dim3(64, 64, G), blk, 0, stream>>>(Pb, P_US, PTb, P_US);
        // attnT[j, v] = PT[j,:] . V[v,:]  -> bf16
        gemm_nt<true><<<dim3(8, 16, G), blk, 0, stream>>>(PTb, P_US, Vb, P_US,
                                                          ATb, P_US, 2048, 1024, 2048);
        // out[d, j] = W_O[d,:] . attnT[j,:]
        gemm_nt<false><<<dim3(16, 8, G), blk, 0, stream>>>(WOb, 0, ATb, P_US,
                                                           out + (size_t)b0 * 2097152, 2097152,
                                                           1024, 2048, 1024);
    }
}

// Round 4
// 574.943 us; speedup vs baseline: 6.0757x; 1.0260x over previous
//
#include <hip/hip_runtime.h>
#include <cstddef>
#include <cstdint>

typedef unsigned short u16;
typedef __attribute__((ext_vector_type(8))) short bf16x8;
typedef __attribute__((ext_vector_type(4))) float f32x4;

#define GLOBAL_AS __attribute__((address_space(1)))
#define LDS_AS __attribute__((address_space(3)))

__device__ __forceinline__ void async16(const u16* g, u16* l) {
    __builtin_amdgcn_global_load_lds((GLOBAL_AS const uint32_t*)g,
                                     (LDS_AS uint32_t*)l, 16, 0, 0);
}

__device__ __forceinline__ u16 f2bf(float f) {
    uint32_t u = __builtin_bit_cast(uint32_t, f);
    uint32_t r = (u + 0x7FFFu + ((u >> 16) & 1u)) >> 16;
    return (u16)r;
}
__device__ __forceinline__ float bf2f(u16 u) {
    return __builtin_bit_cast(float, (uint32_t)u << 16);
}

// ---------------- elementwise prep ----------------
// fp32 -> 3 bf16 planes (same layout); grid*256*4 == element count
__global__ __launch_bounds__(256)
void wsplit3(const float4* __restrict__ src, u16* __restrict__ dst, size_t plane)
{
    int i = blockIdx.x * 256 + threadIdx.x;
    float4 v = src[i];
    u16 a0[4], a1[4], a2[4];
    float c[4] = {v.x, v.y, v.z, v.w};
    #pragma unroll
    for (int k = 0; k < 4; ++k) {
        u16 u0 = f2bf(c[k]);
        float r1 = c[k] - bf2f(u0);
        u16 u1 = f2bf(r1);
        float r2 = r1 - bf2f(u1);
        a0[k] = u0; a1[k] = u1; a2[k] = f2bf(r2);
    }
    *(ushort4*)&dst[4 * (size_t)i]             = *(ushort4*)a0;
    *(ushort4*)&dst[plane + 4 * (size_t)i]     = *(ushort4*)a1;
    *(ushort4*)&dst[2 * plane + 4 * (size_t)i] = *(ushort4*)a2;
}

__global__ __launch_bounds__(256)
void wcast(const float4* __restrict__ src, u16* __restrict__ dst)
{
    int i = blockIdx.x * 256 + threadIdx.x;
    float4 v = src[i];
    ushort4 a = { f2bf(v.x), f2bf(v.y), f2bf(v.z), f2bf(v.w) };
    *(ushort4*)&dst[4 * (size_t)i] = a;
}

// ---------------- transpose + 3-split: src fp32 [R, C] -> dst [C, R] x3 planes ----------------
__global__ __launch_bounds__(256)
void tsplit3(const float* __restrict__ Sb, size_t sBatch,
             u16* __restrict__ Db, size_t dBatch, size_t plane,
             int R, int C)
{
    const float* S = Sb + blockIdx.z * sBatch;
    u16* D = Db + blockIdx.z * dBatch;
    __shared__ float t[32][33];
    int tx = threadIdx.x & 31, ty = threadIdx.x >> 5;
    int c0 = blockIdx.x * 32, r0 = blockIdx.y * 32;
    #pragma unroll
    for (int k = 0; k < 4; ++k)
        t[ty + 8 * k][tx] = S[(size_t)(r0 + ty + 8 * k) * C + c0 + tx];
    __syncthreads();
    #pragma unroll
    for (int k = 0; k < 4; ++k) {
        float a = t[tx][ty + 8 * k];
        u16 u0 = f2bf(a);
        float r1 = a - bf2f(u0);
        u16 u1 = f2bf(r1);
        float r2 = r1 - bf2f(u1);
        size_t o = (size_t)(c0 + ty + 8 * k) * R + r0 + tx;
        D[o] = u0; D[plane + o] = u1; D[2 * plane + o] = f2bf(r2);
    }
}

// transpose + cast: src fp32 [R, C] -> dst bf16 [C, R]
__global__ __launch_bounds__(256)
void tcast(const float* __restrict__ S, u16* __restrict__ D, int R, int C)
{
    __shared__ float t[32][33];
    int tx = threadIdx.x & 31, ty = threadIdx.x >> 5;
    int c0 = blockIdx.x * 32, r0 = blockIdx.y * 32;
    #pragma unroll
    for (int k = 0; k < 4; ++k)
        t[ty + 8 * k][tx] = S[(size_t)(r0 + ty + 8 * k) * C + c0 + tx];
    __syncthreads();
    #pragma unroll
    for (int k = 0; k < 4; ++k)
        D[(size_t)(c0 + ty + 8 * k) * R + r0 + tx] = f2bf(t[tx][ty + 8 * k]);
}

// bf16 [2048,2048] transpose
__global__ __launch_bounds__(256)
void tbf16(const u16* __restrict__ Sb, size_t sBatch, u16* __restrict__ Db, size_t dBatch)
{
    const u16* S = Sb + blockIdx.z * sBatch;
    u16* D = Db + blockIdx.z * dBatch;
    __shared__ u16 t[32][34];
    int tx = threadIdx.x & 31, ty = threadIdx.x >> 5;
    int c0 = blockIdx.x * 32, r0 = blockIdx.y * 32;
    #pragma unroll
    for (int k = 0; k < 4; ++k)
        t[ty + 8 * k][tx] = S[(size_t)(r0 + ty + 8 * k) * 2048 + c0 + tx];
    __syncthreads();
    #pragma unroll
    for (int k = 0; k < 4; ++k)
        D[(size_t)(c0 + ty + 8 * k) * 2048 + r0 + tx] = t[tx][ty + 8 * k];
}

// ---------------- split-3 SIX-term MFMA GEMM ----------------
// C[M,N] fp32 = sum of plane-pairs (00,01,10,11,02,20) of A[M,K] * B[N,K]^T (k-contig)
// Fragments a0,b0,a1,b1 are hoisted to registers: 24 ds_read_b128/wave-kt.
#define MM16(AF, BF)                                                                   \
    _Pragma("unroll") for (int i = 0; i < 4; ++i)                                      \
        _Pragma("unroll") for (int j = 0; j < 4; ++j)                                  \
            acc[i][j] = __builtin_amdgcn_mfma_f32_16x16x32_bf16(AF[i], BF[j], acc[i][j], 0, 0, 0);

__global__ __launch_bounds__(256)
void gemm_s3(const u16* __restrict__ Ab, size_t aBatch, size_t aPlane,
             const u16* __restrict__ Bb, size_t bBatch, size_t bPlane,
             float* __restrict__ Cb, size_t cBatch,
             int M, int N, int K)
{
    __shared__ u16 lds[6][4096];   // A0,A1,A2,B0,B1,B2 tiles: 128 rows x 32 bf16
    const u16* A = Ab + blockIdx.z * aBatch;
    const u16* B = Bb + blockIdx.z * bBatch;
    float* C = Cb + blockIdx.z * cBatch;
    const int tid = threadIdx.x;
    const int lane = tid & 63, wave = tid >> 6;
    const int m0 = blockIdx.y * 128, n0 = blockIdx.x * 128;
    const int l15 = lane & 15, q = lane >> 4;
    const int rm = (wave >> 1) * 64, rn = (wave & 1) * 64;

    // staging: slot s = tid + it*256 -> row s>>2, phys group s&3 holds logical (s&3)^((row>>1)&3)
    int sr[2], sg[2];
    #pragma unroll
    for (int it = 0; it < 2; ++it) {
        int s = tid + it * 256;
        sr[it] = s >> 2;
        sg[it] = (s & 3) ^ ((sr[it] >> 1) & 3);
    }
    const int fsw = q ^ ((l15 >> 1) & 3);
    int aoff[4], boff[4];
    #pragma unroll
    for (int f = 0; f < 4; ++f) {
        aoff[f] = (rm + f * 16 + l15) * 32 + fsw * 8;
        boff[f] = (rn + f * 16 + l15) * 32 + fsw * 8;
    }

    f32x4 acc[4][4];
    #pragma unroll
    for (int i = 0; i < 4; ++i)
        #pragma unroll
        for (int j = 0; j < 4; ++j)
            acc[i][j] = (f32x4){0.f, 0.f, 0.f, 0.f};

    for (int kt = 0; kt < K; kt += 32) {
        #pragma unroll
        for (int p = 0; p < 3; ++p) {
            #pragma unroll
            for (int it = 0; it < 2; ++it) {
                async16(A + p * aPlane + (size_t)(m0 + sr[it]) * K + kt + sg[it] * 8,
                        &lds[p][(it * 256 + wave * 64) * 8]);
                async16(B + p * bPlane + (size_t)(n0 + sr[it]) * K + kt + sg[it] * 8,
                        &lds[3 + p][(it * 256 + wave * 64) * 8]);
            }
        }
        __syncthreads();

        bf16x8 a0f[4], b0f[4], a1f[4], b1f[4], tf[4];
        #pragma unroll
        for (int f = 0; f < 4; ++f) a0f[f] = *(const bf16x8*)&lds[0][aoff[f]];
        #pragma unroll
        for (int f = 0; f < 4; ++f) b0f[f] = *(const bf16x8*)&lds[3][boff[f]];
        MM16(a0f, b0f);                                     // (A0,B0)
        #pragma unroll
        for (int f = 0; f < 4; ++f) b1f[f] = *(const bf16x8*)&lds[4][boff[f]];
        MM16(a0f, b1f);                                     // (A0,B1)
        #pragma unroll
        for (int f = 0; f < 4; ++f) a1f[f] = *(const bf16x8*)&lds[1][aoff[f]];
        MM16(a1f, b0f);                                     // (A1,B0)
        MM16(a1f, b1f);                                     // (A1,B1)
        #pragma unroll
        for (int f = 0; f < 4; ++f) tf[f] = *(const bf16x8*)&lds[5][boff[f]];
        MM16(a0f, tf);                                      // (A0,B2)
        #pragma unroll
        for (int f = 0; f < 4; ++f) tf[f] = *(const bf16x8*)&lds[2][aoff[f]];
        MM16(tf, b0f);                                      // (A2,B0)
        __syncthreads();
    }

    #pragma unroll
    for (int i = 0; i < 4; ++i) {
        int row = m0 + rm + i * 16 + q * 4;
        #pragma unroll
        for (int j = 0; j < 4; ++j) {
            int col = n0 + rn + j * 16 + l15;
            #pragma unroll
            for (int r = 0; r < 4; ++r)
                C[(size_t)(row + r) * N + col] = acc[i][j][r];
        }
    }
}

// ---------------- plain bf16 MFMA GEMM (NT) ----------------
template<bool BF16OUT>
__global__ __launch_bounds__(256)
void gemm_nt(const u16* __restrict__ Ab, size_t aBatch,
             const u16* __restrict__ Bb, size_t bBatch,
             void* __restrict__ Cb, size_t cBatch,
             int M, int N, int K)
{
    __shared__ u16 lds[2][8192];   // 128 rows x 64 bf16 each
    const u16* A = Ab + blockIdx.z * aBatch;
    const u16* B = Bb + blockIdx.z * bBatch;
    const int tid = threadIdx.x;
    const int lane = tid & 63, wave = tid >> 6;
    const int m0 = blockIdx.y * 128, n0 = blockIdx.x * 128;
    const int l15 = lane & 15, q = lane >> 4;
    const int rm = (wave >> 1) * 64, rn = (wave & 1) * 64;

    int sr[4], sg[4];
    #pragma unroll
    for (int it = 0; it < 4; ++it) {
        int s = tid + it * 256;
        sr[it] = s >> 3;
        sg[it] = (s & 7) ^ (sr[it] & 7);
    }
    const int fsw = l15 & 7;
    int aoff[4], boff[4];
    #pragma unroll
    for (int f = 0; f < 4; ++f) {
        aoff[f] = (rm + f * 16 + l15) * 64;
        boff[f] = (rn + f * 16 + l15) * 64;
    }

    f32x4 acc[4][4];
    #pragma unroll
    for (int i = 0; i < 4; ++i)
        #pragma unroll
        for (int j = 0; j < 4; ++j)
            acc[i][j] = (f32x4){0.f, 0.f, 0.f, 0.f};

    for (int kt = 0; kt < K; kt += 64) {
        #pragma unroll
        for (int it = 0; it < 4; ++it) {
            async16(A + (size_t)(m0 + sr[it]) * K + kt + sg[it] * 8,
                    &lds[0][(it * 256 + wave * 64) * 8]);
            async16(B + (size_t)(n0 + sr[it]) * K + kt + sg[it] * 8,
                    &lds[1][(it * 256 + wave * 64) * 8]);
        }
        __syncthreads();
        #pragma unroll
        for (int c = 0; c < 2; ++c) {
            int ga = ((c * 4 + q) ^ fsw) * 8;
            bf16x8 af[4], bfr[4];
            #pragma unroll
            for (int f = 0; f < 4; ++f) af[f] = *(const bf16x8*)&lds[0][aoff[f] + ga];
            #pragma unroll
            for (int f = 0; f < 4; ++f) bfr[f] = *(const bf16x8*)&lds[1][boff[f] + ga];
            #pragma unroll
            for (int i = 0; i < 4; ++i)
                #pragma unroll
                for (int j = 0; j < 4; ++j)
                    acc[i][j] = __builtin_amdgcn_mfma_f32_16x16x32_bf16(af[i], bfr[j], acc[i][j], 0, 0, 0);
        }
        __syncthreads();
    }

    #pragma unroll
    for (int i = 0; i < 4; ++i) {
        int row = m0 + rm + i * 16 + q * 4;
        #pragma unroll
        for (int j = 0; j < 4; ++j) {
            int col = n0 + rn + j * 16 + l15;
            if (BF16OUT) {
                u16* Co = (u16*)Cb + blockIdx.z * cBatch;
                #pragma unroll
                for (int r = 0; r < 4; ++r)
                    Co[(size_t)(row + r) * N + col] = f2bf(acc[i][j][r]);
            } else {
                float* Co = (float*)Cb + blockIdx.z * cBatch;
                #pragma unroll
                for (int r = 0; r < 4; ++r)
                    Co[(size_t)(row + r) * N + col] = acc[i][j][r];
            }
        }
    }
}

// ---------------- row softmax (2048 cols) -> bf16 ----------------
__global__ __launch_bounds__(256)
void softmax_p(const float* __restrict__ Sb, size_t sBatch, u16* __restrict__ Pb, size_t pBatch)
{
    const float* S = Sb + blockIdx.y * sBatch + (size_t)blockIdx.x * 2048;
    u16* P = Pb + blockIdx.y * pBatch + (size_t)blockIdx.x * 2048;
    const int tid = threadIdx.x;

    float4 v0 = *(const float4*)&S[tid * 4];
    float4 v1 = *(const float4*)&S[1024 + tid * 4];

    float m = fmaxf(fmaxf(fmaxf(v0.x, v0.y), fmaxf(v0.z, v0.w)),
                    fmaxf(fmaxf(v1.x, v1.y), fmaxf(v1.z, v1.w)));
    #pragma unroll
    for (int off = 32; off > 0; off >>= 1)
        m = fmaxf(m, __shfl_xor(m, off, 64));
    __shared__ float redm[4];
    if ((tid & 63) == 0) redm[tid >> 6] = m;
    __syncthreads();
    m = fmaxf(fmaxf(redm[0], redm[1]), fmaxf(redm[2], redm[3]));

    v0.x = __expf(v0.x - m); v0.y = __expf(v0.y - m);
    v0.z = __expf(v0.z - m); v0.w = __expf(v0.w - m);
    v1.x = __expf(v1.x - m); v1.y = __expf(v1.y - m);
    v1.z = __expf(v1.z - m); v1.w = __expf(v1.w - m);

    float s = v0.x + v0.y + v0.z + v0.w + v1.x + v1.y + v1.z + v1.w;
    #pragma unroll
    for (int off = 32; off > 0; off >>= 1)
        s += __shfl_xor(s, off, 64);
    __shared__ float reds[4];
    if ((tid & 63) == 0) reds[tid >> 6] = s;
    __syncthreads();
    s = reds[0] + reds[1] + reds[2] + reds[3];

    const float r = 1.0f / s;
    ushort4 o0 = { f2bf(v0.x * r), f2bf(v0.y * r), f2bf(v0.z * r), f2bf(v0.w * r) };
    ushort4 o1 = { f2bf(v1.x * r), f2bf(v1.y * r), f2bf(v1.z * r), f2bf(v1.w * r) };
    *(ushort4*)&P[tid * 4] = o0;
    *(ushort4*)&P[1024 + tid * 4] = o1;
}

// ---------------- driver ----------------
extern "C" void kernel_launch(void* const* d_in, const int* in_sizes, int n_in,
                              void* d_out, int out_size, void* d_ws, size_t ws_size,
                              hipStream_t stream)
{
    const size_t MB = 1048576;
    const size_t WREG = 24 * MB;           // M3(6) + WOV(2) + xb_bf(16)
    const size_t PER  = 40 * MB;           // per-batch region
    const size_t PER_US = PER / 2, PER_F = PER / 4;

    char* ws = (char*)d_ws;
    u16*   M3    = (u16*)ws;               // 3 planes, plane stride 1048576 u16
    u16*   WOV   = (u16*)(ws + 6 * MB);
    u16*   xbf   = (u16*)(ws + 8 * MB);    // all 4 batches, bf16 [1024,2048] each

    // prep scratch lives in batch-region 0 (free before the batch loop runs)
    char* SC = ws + WREG;
    u16*   WQT3 = (u16*)SC;                // 6 MB
    u16*   WKT3 = (u16*)(SC + 6 * MB);     // 6 MB
    float* M32  = (float*)(SC + 12 * MB);  // 4 MB
    u16*   WVT  = (u16*)(SC + 16 * MB);    // 2 MB
    u16*   WObf = (u16*)(SC + 18 * MB);    // 2 MB

    int G = (ws_size >= WREG + 4 * PER) ? 4 : (ws_size >= WREG + 2 * PER) ? 2 : 1;

    const float* x = (const float*)d_in[0];
    float* out = (float*)d_out;
    dim3 blk(256);

    // ---- weight prep (once) ----
    tsplit3<<<dim3(32, 32, 1), blk, 0, stream>>>((const float*)d_in[1], 0, WQT3, 0, 1048576, 1024, 1024);
    tsplit3<<<dim3(32, 32, 1), blk, 0, stream>>>((const float*)d_in[2], 0, WKT3, 0, 1048576, 1024, 1024);
    // M[d,d'] = sum_h W_K[h,d] * W_Q[h,d']
    gemm_s3<<<dim3(8, 8, 1), blk, 0, stream>>>(WKT3, 0, 1048576, WQT3, 0, 1048576,
                                               M32, 0, 1024, 1024, 1024);
    wsplit3<<<1024, blk, 0, stream>>>((const float4*)M32, M3, 1048576);
    tcast<<<dim3(32, 32, 1), blk, 0, stream>>>((const float*)d_in[3], WVT, 1024, 1024);
    wcast<<<1024, blk, 0, stream>>>((const float4*)d_in[4], WObf);
    // WOV[d,d'] = sum_v W_O[d,v] * W_V[v,d']
    gemm_nt<true><<<dim3(8, 8, 1), blk, 0, stream>>>(WObf, 0, WVT, 0, WOV, 0, 1024, 1024, 1024);
    // x -> bf16 (all batches)
    wcast<<<8192, blk, 0, stream>>>((const float4*)x, xbf);

    for (int b0 = 0; b0 < 4; b0 += G) {
        char* R = ws + WREG;               // z-indexed regions, stride PER
        u16*   xT3 = (u16*)R;                      // 12 MB, plane 2097152 u16
        u16*   TT3 = (u16*)(R + 12 * MB);          // 12 MB
        float* T32 = (float*)(R + 24 * MB);        // 8 MB (inside S32 region)
        float* S32 = (float*)(R + 24 * MB);        // 16 MB
        u16*   Pb  = (u16*)R;                      // 8 MB (over dead xT3)
        u16*   PTb = (u16*)(R + 12 * MB);          // 8 MB (over dead TT3)
        u16*   XPT = (u16*)R;                      // 4 MB (over dead Pb)

        // x -> xT3 [i, d] 3 planes
        tsplit3<<<dim3(64, 32, G), blk, 0, stream>>>(x + (size_t)b0 * 2097152, 2097152,
                                                     xT3, PER_US, 2097152, 1024, 2048);
        // T = M x  [d, j] fp32
        gemm_s3<<<dim3(16, 8, G), blk, 0, stream>>>(M3, 0, 1048576, xT3, PER_US, 2097152,
                                                    T32, PER_F, 1024, 2048, 1024);
        // T -> TT3 [j, d] 3 planes
        tsplit3<<<dim3(64, 32, G), blk, 0, stream>>>(T32, PER_F, TT3, PER_US, 2097152, 1024, 2048);
        // S[i,j] = sum_d xT[i,d] * TT[j,d]
        gemm_s3<<<dim3(16, 16, G), blk, 0, stream>>>(xT3, PER_US, 2097152, TT3, PER_US, 2097152,
                                                     S32, PER_F, 2048, 2048, 1024);
        // softmax rows -> P bf16 [i, j]
        softmax_p<<<dim3(2048, G), blk, 0, stream>>>(S32, PER_F, Pb, PER_US);
        // P -> PT [j, i]
        tbf16<<<dim3(64, 64, G), blk, 0, stream>>>(Pb, PER_US, PTb, PER_US);
        // XPT[j,d'] = sum_i PT[j,i] * x[d',i]  -> bf16 [2048, 1024]
        gemm_nt<true><<<dim3(8, 16, G), blk, 0, stream>>>(PTb, PER_US, xbf + (size_t)b0 * 2097152, 2097152,
                                                          XPT, PER_US, 2048, 1024, 2048);
        // out[d,j] = sum_d' WOV[d,d'] * XPT[j,d']
        gemm_nt<false><<<dim3(16, 8, G), blk, 0, stream>>>(WOV, 0, XPT, PER_US,
                                                           out + (size_t)b0 * 2097152, 2097152,
                                                           1024, 2048, 1024);
    }
}

// Round 5
// 423.757 us; speedup vs baseline: 8.2434x; 1.3568x over previous
//
#include <hip/hip_runtime.h>
#include <cstddef>
#include <cstdint>

typedef unsigned short u16;
typedef __attribute__((ext_vector_type(8))) short bf16x8;
typedef __attribute__((ext_vector_type(8))) _Float16 f16x8;
typedef __attribute__((ext_vector_type(4))) float f32x4;

#define GLOBAL_AS __attribute__((address_space(1)))
#define LDS_AS __attribute__((address_space(3)))

__device__ __forceinline__ void async16(const u16* g, u16* l) {
    __builtin_amdgcn_global_load_lds((GLOBAL_AS const uint32_t*)g,
                                     (LDS_AS uint32_t*)l, 16, 0, 0);
}

__device__ __forceinline__ u16 f2bf(float f) {
    uint32_t u = __builtin_bit_cast(uint32_t, f);
    uint32_t r = (u + 0x7FFFu + ((u >> 16) & 1u)) >> 16;
    return (u16)r;
}

// ---------------- elementwise prep ----------------
__global__ __launch_bounds__(256)
void wcast(const float4* __restrict__ src, u16* __restrict__ dst)
{
    int i = blockIdx.x * 256 + threadIdx.x;
    float4 v = src[i];
    ushort4 a = { f2bf(v.x), f2bf(v.y), f2bf(v.z), f2bf(v.w) };
    *(ushort4*)&dst[4 * (size_t)i] = a;
}

// transpose + f16 2-split with x64 scale: fp32 [R,C] -> [C,R] planes h0,h1 of 64*v
__global__ __launch_bounds__(256)
void tsplit_h2(const float* __restrict__ Sb, size_t sBatch,
               u16* __restrict__ Db, size_t dBatch, size_t plane,
               int R, int C)
{
    const float* S = Sb + blockIdx.z * sBatch;
    u16* D = Db + blockIdx.z * dBatch;
    __shared__ float t[32][33];
    int tx = threadIdx.x & 31, ty = threadIdx.x >> 5;
    int c0 = blockIdx.x * 32, r0 = blockIdx.y * 32;
    #pragma unroll
    for (int k = 0; k < 4; ++k)
        t[ty + 8 * k][tx] = S[(size_t)(r0 + ty + 8 * k) * C + c0 + tx];
    __syncthreads();
    #pragma unroll
    for (int k = 0; k < 4; ++k) {
        float a = t[tx][ty + 8 * k] * 64.0f;
        _Float16 h0 = (_Float16)a;
        _Float16 h1 = (_Float16)(a - (float)h0);
        size_t o = (size_t)(c0 + ty + 8 * k) * R + r0 + tx;
        D[o] = __builtin_bit_cast(u16, h0);
        D[plane + o] = __builtin_bit_cast(u16, h1);
    }
}

// transpose + cast: fp32 [R,C] -> bf16 [C,R]
__global__ __launch_bounds__(256)
void tcast(const float* __restrict__ S, u16* __restrict__ D, int R, int C)
{
    __shared__ float t[32][33];
    int tx = threadIdx.x & 31, ty = threadIdx.x >> 5;
    int c0 = blockIdx.x * 32, r0 = blockIdx.y * 32;
    #pragma unroll
    for (int k = 0; k < 4; ++k)
        t[ty + 8 * k][tx] = S[(size_t)(r0 + ty + 8 * k) * C + c0 + tx];
    __syncthreads();
    #pragma unroll
    for (int k = 0; k < 4; ++k)
        D[(size_t)(c0 + ty + 8 * k) * R + r0 + tx] = f2bf(t[tx][ty + 8 * k]);
}

// bf16 [2048,2048] transpose
__global__ __launch_bounds__(256)
void tbf16(const u16* __restrict__ Sb, size_t sBatch, u16* __restrict__ Db, size_t dBatch)
{
    const u16* S = Sb + blockIdx.z * sBatch;
    u16* D = Db + blockIdx.z * dBatch;
    __shared__ u16 t[32][34];
    int tx = threadIdx.x & 31, ty = threadIdx.x >> 5;
    int c0 = blockIdx.x * 32, r0 = blockIdx.y * 32;
    #pragma unroll
    for (int k = 0; k < 4; ++k)
        t[ty + 8 * k][tx] = S[(size_t)(r0 + ty + 8 * k) * 2048 + c0 + tx];
    __syncthreads();
    #pragma unroll
    for (int k = 0; k < 4; ++k)
        D[(size_t)(c0 + ty + 8 * k) * 2048 + r0 + tx] = t[tx][ty + 8 * k];
}

// ---------------- unified double-buffered MFMA GEMM ----------------
// C[M,N] = op over A[M,K] * B[N,K]^T (k-contig rows, BK=32).
// TERMS=3: A,B are f16 2-plane splits; terms (00,01,10).
// TERMS=1: A,B single bf16 plane.
// EPI: 0 = fp32 out; 1 = f16 2-split of acc*2^-12; 2 = bf16 out.
#define MMF(AF, BF)                                                                    \
    _Pragma("unroll") for (int i = 0; i < 4; ++i)                                      \
        _Pragma("unroll") for (int j = 0; j < 4; ++j)                                  \
            acc[i][j] = __builtin_amdgcn_mfma_f32_16x16x32_f16(AF[i], BF[j], acc[i][j], 0, 0, 0);
#define MMB(AF, BF)                                                                    \
    _Pragma("unroll") for (int i = 0; i < 4; ++i)                                      \
        _Pragma("unroll") for (int j = 0; j < 4; ++j)                                  \
            acc[i][j] = __builtin_amdgcn_mfma_f32_16x16x32_bf16(AF[i], BF[j], acc[i][j], 0, 0, 0);

template<int TERMS, int EPI>
__global__ __launch_bounds__(256)
void gemm_big(const u16* __restrict__ Ab, size_t aBatch, size_t aPlane,
              const u16* __restrict__ Bb, size_t bBatch, size_t bPlane,
              void* __restrict__ Cb, size_t cBatch, size_t cPlane,
              int M, int N, int K)
{
    constexpr int RSZ = 4096;                       // u16 per plane-region (128 rows x 32)
    constexpr int BUF = (TERMS == 3 ? 4 : 2) * RSZ; // u16 per buffer
    __shared__ u16 lds[2 * BUF];
    const u16* A = Ab + blockIdx.z * aBatch;
    const u16* B = Bb + blockIdx.z * bBatch;
    const int tid = threadIdx.x;
    const int lane = tid & 63, wave = tid >> 6;
    const int m0 = blockIdx.y * 128, n0 = blockIdx.x * 128;
    const int l15 = lane & 15, q = lane >> 4;
    const int rm = (wave >> 1) * 64, rn = (wave & 1) * 64;

    // staging: slot s -> row s>>2; phys group s&3 holds logical (s&3)^((row>>1)&3)
    int sr[2], sg[2], sbase[2];
    #pragma unroll
    for (int it = 0; it < 2; ++it) {
        int s = tid + it * 256;
        sr[it] = s >> 2;
        sg[it] = (s & 3) ^ ((sr[it] >> 1) & 3);
        sbase[it] = (it * 256 + wave * 64) * 8;     // wave-uniform LDS slot base
    }
    const int fsw = (q ^ ((l15 >> 1) & 3)) * 8;
    int aoff[4], boff[4];
    #pragma unroll
    for (int f = 0; f < 4; ++f) {
        aoff[f] = (rm + f * 16 + l15) * 32 + fsw;
        boff[f] = (rn + f * 16 + l15) * 32 + fsw;
    }

    f32x4 acc[4][4];
    #pragma unroll
    for (int i = 0; i < 4; ++i)
        #pragma unroll
        for (int j = 0; j < 4; ++j)
            acc[i][j] = (f32x4){0.f, 0.f, 0.f, 0.f};

#define STAGE(PP, KT)                                                                  \
    do {                                                                               \
        _Pragma("unroll")                                                              \
        for (int it = 0; it < 2; ++it) {                                               \
            const size_t ao = (size_t)(m0 + sr[it]) * K + (KT) + sg[it] * 8;           \
            const size_t bo = (size_t)(n0 + sr[it]) * K + (KT) + sg[it] * 8;           \
            const int d = (PP) * BUF + sbase[it];                                      \
            if (TERMS == 3) {                                                          \
                async16(A + ao, &lds[d]);                                              \
                async16(A + aPlane + ao, &lds[d + RSZ]);                               \
                async16(B + bo, &lds[d + 2 * RSZ]);                                    \
                async16(B + bPlane + bo, &lds[d + 3 * RSZ]);                           \
            } else {                                                                   \
                async16(A + ao, &lds[d]);                                              \
                async16(B + bo, &lds[d + RSZ]);                                        \
            }                                                                          \
        }                                                                              \
    } while (0)

    STAGE(0, 0);
    for (int kt = 0; kt < K; kt += 32) {
        const int p = (kt >> 5) & 1;
        __syncthreads();                        // buf p ready; buf p^1 free
        if (kt + 32 < K) STAGE(p ^ 1, kt + 32); // prefetch next tile
        const u16* L = &lds[p * BUF];
        if (TERMS == 3) {
            f16x8 a0f[4], b0f[4], xf[4];
            #pragma unroll
            for (int f = 0; f < 4; ++f) a0f[f] = *(const f16x8*)&L[aoff[f]];
            #pragma unroll
            for (int f = 0; f < 4; ++f) b0f[f] = *(const f16x8*)&L[2 * RSZ + boff[f]];
            MMF(a0f, b0f);                                   // h0*h0
            #pragma unroll
            for (int f = 0; f < 4; ++f) xf[f] = *(const f16x8*)&L[3 * RSZ + boff[f]];
            MMF(a0f, xf);                                    // h0*h1
            #pragma unroll
            for (int f = 0; f < 4; ++f) xf[f] = *(const f16x8*)&L[RSZ + aoff[f]];
            MMF(xf, b0f);                                    // h1*h0
        } else {
            bf16x8 af[4], bf_[4];
            #pragma unroll
            for (int f = 0; f < 4; ++f) af[f] = *(const bf16x8*)&L[aoff[f]];
            #pragma unroll
            for (int f = 0; f < 4; ++f) bf_[f] = *(const bf16x8*)&L[RSZ + boff[f]];
            MMB(af, bf_);
        }
    }
#undef STAGE

    #pragma unroll
    for (int i = 0; i < 4; ++i) {
        int row = m0 + rm + i * 16 + q * 4;
        #pragma unroll
        for (int j = 0; j < 4; ++j) {
            int col = n0 + rn + j * 16 + l15;
            #pragma unroll
            for (int r = 0; r < 4; ++r) {
                float v = acc[i][j][r];
                size_t o = (size_t)(row + r) * N + col;
                if (EPI == 0) {
                    ((float*)Cb + blockIdx.z * cBatch)[o] = v;
                } else if (EPI == 1) {
                    u16* C0 = (u16*)Cb + blockIdx.z * cBatch;
                    float vs = v * 0.000244140625f;          // * 2^-12
                    _Float16 h0 = (_Float16)vs;
                    _Float16 h1 = (_Float16)(vs - (float)h0);
                    C0[o] = __builtin_bit_cast(u16, h0);
                    C0[cPlane + o] = __builtin_bit_cast(u16, h1);
                } else {
                    ((u16*)Cb + blockIdx.z * cBatch)[o] = f2bf(v);
                }
            }
        }
    }
}

// ---------------- row softmax (2048 cols) -> bf16 ----------------
__global__ __launch_bounds__(256)
void softmax_p(const float* __restrict__ Sb, size_t sBatch, u16* __restrict__ Pb, size_t pBatch)
{
    const float* S = Sb + blockIdx.y * sBatch + (size_t)blockIdx.x * 2048;
    u16* P = Pb + blockIdx.y * pBatch + (size_t)blockIdx.x * 2048;
    const int tid = threadIdx.x;

    float4 v0 = *(const float4*)&S[tid * 4];
    float4 v1 = *(const float4*)&S[1024 + tid * 4];

    float m = fmaxf(fmaxf(fmaxf(v0.x, v0.y), fmaxf(v0.z, v0.w)),
                    fmaxf(fmaxf(v1.x, v1.y), fmaxf(v1.z, v1.w)));
    #pragma unroll
    for (int off = 32; off > 0; off >>= 1)
        m = fmaxf(m, __shfl_xor(m, off, 64));
    __shared__ float redm[4];
    if ((tid & 63) == 0) redm[tid >> 6] = m;
    __syncthreads();
    m = fmaxf(fmaxf(redm[0], redm[1]), fmaxf(redm[2], redm[3]));

    v0.x = __expf(v0.x - m); v0.y = __expf(v0.y - m);
    v0.z = __expf(v0.z - m); v0.w = __expf(v0.w - m);
    v1.x = __expf(v1.x - m); v1.y = __expf(v1.y - m);
    v1.z = __expf(v1.z - m); v1.w = __expf(v1.w - m);

    float s = v0.x + v0.y + v0.z + v0.w + v1.x + v1.y + v1.z + v1.w;
    #pragma unroll
    for (int off = 32; off > 0; off >>= 1)
        s += __shfl_xor(s, off, 64);
    __shared__ float reds[4];
    if ((tid & 63) == 0) reds[tid >> 6] = s;
    __syncthreads();
    s = reds[0] + reds[1] + reds[2] + reds[3];

    const float r = 1.0f / s;
    ushort4 o0 = { f2bf(v0.x * r), f2bf(v0.y * r), f2bf(v0.z * r), f2bf(v0.w * r) };
    ushort4 o1 = { f2bf(v1.x * r), f2bf(v1.y * r), f2bf(v1.z * r), f2bf(v1.w * r) };
    *(ushort4*)&P[tid * 4] = o0;
    *(ushort4*)&P[1024 + tid * 4] = o1;
}

// ---------------- driver ----------------
extern "C" void kernel_launch(void* const* d_in, const int* in_sizes, int n_in,
                              void* d_out, int out_size, void* d_ws, size_t ws_size,
                              hipStream_t stream)
{
    const size_t MB = 1048576;
    const size_t WREG = 34 * MB;           // weights + xbf
    const size_t PER  = 32 * MB;           // per-batch region
    const size_t PER_US = PER / 2, PER_F = PER / 4;

    char* ws = (char*)d_ws;
    u16* WQT2 = (u16*)ws;                  // [d',h] x64, plane 1048576 u16 (4 MB)
    u16* WKT2 = (u16*)(ws + 4 * MB);       // [d,h]  x64 (4 MB)
    u16* M2   = (u16*)(ws + 8 * MB);       // [d,d'] split(M), plane 1048576 (4 MB)
    u16* WObf = (u16*)(ws + 12 * MB);      // bf16 [d,v] (2 MB)
    u16* WVT  = (u16*)(ws + 14 * MB);      // bf16 [d',v] (2 MB)
    u16* WOV  = (u16*)(ws + 16 * MB);      // bf16 [d,d'] (2 MB)
    u16* xbf  = (u16*)(ws + 18 * MB);      // bf16 [d,i] all batches (16 MB)

    int G = (ws_size >= WREG + 4 * PER) ? 4 : (ws_size >= WREG + 2 * PER) ? 2 : 1;

    const float* x = (const float*)d_in[0];
    float* out = (float*)d_out;
    dim3 blk(256);

    // ---- weight prep (once) ----
    tsplit_h2<<<dim3(32, 32, 1), blk, 0, stream>>>((const float*)d_in[1], 0, WQT2, 0, 1048576, 1024, 1024);
    tsplit_h2<<<dim3(32, 32, 1), blk, 0, stream>>>((const float*)d_in[2], 0, WKT2, 0, 1048576, 1024, 1024);
    // M = W_K^T W_Q: acc = 4096*M, EPI=1 scales by 2^-12 -> planes = split(M)
    gemm_big<3, 1><<<dim3(8, 8, 1), blk, 0, stream>>>(WKT2, 0, 1048576, WQT2, 0, 1048576,
                                                      M2, 0, 1048576, 1024, 1024, 1024);
    wcast<<<1024, blk, 0, stream>>>((const float4*)d_in[4], WObf);
    tcast<<<dim3(32, 32, 1), blk, 0, stream>>>((const float*)d_in[3], WVT, 1024, 1024);
    // WOV = W_O W_V (bf16)
    gemm_big<1, 2><<<dim3(8, 8, 1), blk, 0, stream>>>(WObf, 0, 0, WVT, 0, 0,
                                                      WOV, 0, 0, 1024, 1024, 1024);
    wcast<<<8192, blk, 0, stream>>>((const float4*)x, xbf);

    for (int b0 = 0; b0 < 4; b0 += G) {
        char* R = ws + WREG;               // z-indexed regions, stride PER
        u16*   xT2 = (u16*)R;              // [i,d] x64 split, plane 2097152 u16 (8 MB)
        u16*   TT2 = (u16*)(R + 8 * MB);   // [j,d] split(T/64), plane 2097152 (8 MB)
        float* S32 = (float*)(R + 16 * MB);// fp32 [i,j] (16 MB)
        u16*   Pb  = (u16*)R;              // bf16 [i,j] (8 MB, over dead xT2)
        u16*   PTb = (u16*)(R + 8 * MB);   // bf16 [j,i] (8 MB, over dead TT2)
        u16*   XPT = (u16*)(R + 16 * MB);  // bf16 [j,d'] (4 MB, over dead S32)

        // x -> xT2 (64x, f16 2-plane, [i,d])
        tsplit_h2<<<dim3(64, 32, G), blk, 0, stream>>>(x + (size_t)b0 * 2097152, 2097152,
                                                       xT2, PER_US, 2097152, 1024, 2048);
        // T^T = (64x)^T M -> acc = 64T; EPI=1 -> planes = split(T/64) in [j,d]
        gemm_big<3, 1><<<dim3(8, 16, G), blk, 0, stream>>>(xT2, PER_US, 2097152, M2, 0, 1048576,
                                                           TT2, PER_US, 2097152, 2048, 1024, 1024);
        // S[i,j] = (64x)^T[i,:] . (T/64)[j,:]
        gemm_big<3, 0><<<dim3(16, 16, G), blk, 0, stream>>>(xT2, PER_US, 2097152, TT2, PER_US, 2097152,
                                                            S32, PER_F, 0, 2048, 2048, 1024);
        // softmax rows -> P bf16
        softmax_p<<<dim3(2048, G), blk, 0, stream>>>(S32, PER_F, Pb, PER_US);
        // P -> PT
        tbf16<<<dim3(64, 64, G), blk, 0, stream>>>(Pb, PER_US, PTb, PER_US);
        // XPT[j,d'] = PT[j,:] . xbf[d',:]
        gemm_big<1, 2><<<dim3(8, 16, G), blk, 0, stream>>>(PTb, PER_US, 0,
                                                           xbf + (size_t)b0 * 2097152, 2097152, 0,
                                                           XPT, PER_US, 0, 2048, 1024, 2048);
        // out[d,j] = WOV[d,:] . XPT[j,:]
        gemm_big<1, 0><<<dim3(16, 8, G), blk, 0, stream>>>(WOV, 0, 0, XPT, PER_US, 0,
                                                           out + (size_t)b0 * 2097152, 2097152, 0,
                                                           1024, 2048, 1024);
    }
}

// Round 6
// 416.069 us; speedup vs baseline: 8.3957x; 1.0185x over previous
//
#include <hip/hip_runtime.h>
#include <cstddef>
#include <cstdint>

typedef unsigned short u16;
typedef __attribute__((ext_vector_type(8))) short bf16x8;
typedef __attribute__((ext_vector_type(8))) _Float16 f16x8;
typedef __attribute__((ext_vector_type(4))) float f32x4;

#define GLOBAL_AS __attribute__((address_space(1)))
#define LDS_AS __attribute__((address_space(3)))

__device__ __forceinline__ void async16(const u16* g, u16* l) {
    __builtin_amdgcn_global_load_lds((GLOBAL_AS const uint32_t*)g,
                                     (LDS_AS uint32_t*)l, 16, 0, 0);
}

__device__ __forceinline__ u16 f2bf(float f) {
    uint32_t u = __builtin_bit_cast(uint32_t, f);
    uint32_t r = (u + 0x7FFFu + ((u >> 16) & 1u)) >> 16;
    return (u16)r;
}

// ---------------- elementwise prep ----------------
__global__ __launch_bounds__(256)
void wcast(const float4* __restrict__ src, u16* __restrict__ dst)
{
    int i = blockIdx.x * 256 + threadIdx.x;
    float4 v = src[i];
    ushort4 a = { f2bf(v.x), f2bf(v.y), f2bf(v.z), f2bf(v.w) };
    *(ushort4*)&dst[4 * (size_t)i] = a;
}

// transpose + f16 2-split with x64 scale: fp32 [R,C] -> [C,R] planes h0,h1 of 64*v
__global__ __launch_bounds__(256)
void tsplit_h2(const float* __restrict__ Sb, size_t sBatch,
               u16* __restrict__ Db, size_t dBatch, size_t plane,
               int R, int C)
{
    const float* S = Sb + blockIdx.z * sBatch;
    u16* D = Db + blockIdx.z * dBatch;
    __shared__ float t[32][33];
    int tx = threadIdx.x & 31, ty = threadIdx.x >> 5;
    int c0 = blockIdx.x * 32, r0 = blockIdx.y * 32;
    #pragma unroll
    for (int k = 0; k < 4; ++k)
        t[ty + 8 * k][tx] = S[(size_t)(r0 + ty + 8 * k) * C + c0 + tx];
    __syncthreads();
    #pragma unroll
    for (int k = 0; k < 4; ++k) {
        float a = t[tx][ty + 8 * k] * 64.0f;
        _Float16 h0 = (_Float16)a;
        _Float16 h1 = (_Float16)(a - (float)h0);
        size_t o = (size_t)(c0 + ty + 8 * k) * R + r0 + tx;
        D[o] = __builtin_bit_cast(u16, h0);
        D[plane + o] = __builtin_bit_cast(u16, h1);
    }
}

// transpose + cast: fp32 [R,C] -> bf16 [C,R]
__global__ __launch_bounds__(256)
void tcast(const float* __restrict__ S, u16* __restrict__ D, int R, int C)
{
    __shared__ float t[32][33];
    int tx = threadIdx.x & 31, ty = threadIdx.x >> 5;
    int c0 = blockIdx.x * 32, r0 = blockIdx.y * 32;
    #pragma unroll
    for (int k = 0; k < 4; ++k)
        t[ty + 8 * k][tx] = S[(size_t)(r0 + ty + 8 * k) * C + c0 + tx];
    __syncthreads();
    #pragma unroll
    for (int k = 0; k < 4; ++k)
        D[(size_t)(c0 + ty + 8 * k) * R + r0 + tx] = f2bf(t[tx][ty + 8 * k]);
}

// bf16 [2048,2048] transpose
__global__ __launch_bounds__(256)
void tbf16(const u16* __restrict__ Sb, size_t sBatch, u16* __restrict__ Db, size_t dBatch)
{
    const u16* S = Sb + blockIdx.z * sBatch;
    u16* D = Db + blockIdx.z * dBatch;
    __shared__ u16 t[32][34];
    int tx = threadIdx.x & 31, ty = threadIdx.x >> 5;
    int c0 = blockIdx.x * 32, r0 = blockIdx.y * 32;
    #pragma unroll
    for (int k = 0; k < 4; ++k)
        t[ty + 8 * k][tx] = S[(size_t)(r0 + ty + 8 * k) * 2048 + c0 + tx];
    __syncthreads();
    #pragma unroll
    for (int k = 0; k < 4; ++k)
        D[(size_t)(c0 + ty + 8 * k) * 2048 + r0 + tx] = t[tx][ty + 8 * k];
}

// ---------------- 128-tile MFMA GEMM (weight prep only, 256 thr) ----------------
#define MMF4(AF, BF)                                                                   \
    _Pragma("unroll") for (int i = 0; i < 4; ++i)                                      \
        _Pragma("unroll") for (int j = 0; j < 4; ++j)                                  \
            acc[i][j] = __builtin_amdgcn_mfma_f32_16x16x32_f16(AF[i], BF[j], acc[i][j], 0, 0, 0);
#define MMB4(AF, BF)                                                                   \
    _Pragma("unroll") for (int i = 0; i < 4; ++i)                                      \
        _Pragma("unroll") for (int j = 0; j < 4; ++j)                                  \
            acc[i][j] = __builtin_amdgcn_mfma_f32_16x16x32_bf16(AF[i], BF[j], acc[i][j], 0, 0, 0);

template<int TERMS, int EPI>
__global__ __launch_bounds__(256)
void gemm_big(const u16* __restrict__ Ab, size_t aBatch, size_t aPlane,
              const u16* __restrict__ Bb, size_t bBatch, size_t bPlane,
              void* __restrict__ Cb, size_t cBatch, size_t cPlane,
              int M, int N, int K)
{
    constexpr int RSZ = 4096;
    constexpr int BUF = (TERMS == 3 ? 4 : 2) * RSZ;
    __shared__ u16 lds[2 * BUF];
    const u16* A = Ab + blockIdx.z * aBatch;
    const u16* B = Bb + blockIdx.z * bBatch;
    const int tid = threadIdx.x;
    const int lane = tid & 63, wave = tid >> 6;
    const int m0 = blockIdx.y * 128, n0 = blockIdx.x * 128;
    const int l15 = lane & 15, q = lane >> 4;
    const int rm = (wave >> 1) * 64, rn = (wave & 1) * 64;

    int sr[2], sg[2], sbase[2];
    #pragma unroll
    for (int it = 0; it < 2; ++it) {
        int s = tid + it * 256;
        sr[it] = s >> 2;
        sg[it] = (s & 3) ^ ((sr[it] >> 1) & 3);
        sbase[it] = (it * 256 + wave * 64) * 8;
    }
    const int fsw = (q ^ ((l15 >> 1) & 3)) * 8;
    int aoff[4], boff[4];
    #pragma unroll
    for (int f = 0; f < 4; ++f) {
        aoff[f] = (rm + f * 16 + l15) * 32 + fsw;
        boff[f] = (rn + f * 16 + l15) * 32 + fsw;
    }

    f32x4 acc[4][4];
    #pragma unroll
    for (int i = 0; i < 4; ++i)
        #pragma unroll
        for (int j = 0; j < 4; ++j)
            acc[i][j] = (f32x4){0.f, 0.f, 0.f, 0.f};

#define STAGEB(PP, KT)                                                                 \
    do {                                                                               \
        _Pragma("unroll")                                                              \
        for (int it = 0; it < 2; ++it) {                                               \
            const size_t ao = (size_t)(m0 + sr[it]) * K + (KT) + sg[it] * 8;           \
            const size_t bo = (size_t)(n0 + sr[it]) * K + (KT) + sg[it] * 8;           \
            const int d = (PP) * BUF + sbase[it];                                      \
            if (TERMS == 3) {                                                          \
                async16(A + ao, &lds[d]);                                              \
                async16(A + aPlane + ao, &lds[d + RSZ]);                               \
                async16(B + bo, &lds[d + 2 * RSZ]);                                    \
                async16(B + bPlane + bo, &lds[d + 3 * RSZ]);                           \
            } else {                                                                   \
                async16(A + ao, &lds[d]);                                              \
                async16(B + bo, &lds[d + RSZ]);                                        \
            }                                                                          \
        }                                                                              \
    } while (0)

    STAGEB(0, 0);
    for (int kt = 0; kt < K; kt += 32) {
        const int p = (kt >> 5) & 1;
        __syncthreads();
        if (kt + 32 < K) STAGEB(p ^ 1, kt + 32);
        const u16* L = &lds[p * BUF];
        if (TERMS == 3) {
            f16x8 a0f[4], b0f[4], xf[4];
            #pragma unroll
            for (int f = 0; f < 4; ++f) a0f[f] = *(const f16x8*)&L[aoff[f]];
            #pragma unroll
            for (int f = 0; f < 4; ++f) b0f[f] = *(const f16x8*)&L[2 * RSZ + boff[f]];
            MMF4(a0f, b0f);
            #pragma unroll
            for (int f = 0; f < 4; ++f) xf[f] = *(const f16x8*)&L[3 * RSZ + boff[f]];
            MMF4(a0f, xf);
            #pragma unroll
            for (int f = 0; f < 4; ++f) xf[f] = *(const f16x8*)&L[RSZ + aoff[f]];
            MMF4(xf, b0f);
        } else {
            bf16x8 af[4], bf_[4];
            #pragma unroll
            for (int f = 0; f < 4; ++f) af[f] = *(const bf16x8*)&L[aoff[f]];
            #pragma unroll
            for (int f = 0; f < 4; ++f) bf_[f] = *(const bf16x8*)&L[RSZ + boff[f]];
            MMB4(af, bf_);
        }
    }
#undef STAGEB

    #pragma unroll
    for (int i = 0; i < 4; ++i) {
        int row = m0 + rm + i * 16 + q * 4;
        #pragma unroll
        for (int j = 0; j < 4; ++j) {
            int col = n0 + rn + j * 16 + l15;
            #pragma unroll
            for (int r = 0; r < 4; ++r) {
                float v = acc[i][j][r];
                size_t o = (size_t)(row + r) * N + col;
                if (EPI == 0) {
                    ((float*)Cb + blockIdx.z * cBatch)[o] = v;
                } else if (EPI == 1) {
                    u16* C0 = (u16*)Cb + blockIdx.z * cBatch;
                    float vs = v * 0.000244140625f;
                    _Float16 h0 = (_Float16)vs;
                    _Float16 h1 = (_Float16)(vs - (float)h0);
                    C0[o] = __builtin_bit_cast(u16, h0);
                    C0[cPlane + o] = __builtin_bit_cast(u16, h1);
                } else {
                    ((u16*)Cb + blockIdx.z * cBatch)[o] = f2bf(v);
                }
            }
        }
    }
}

// ---------------- wide-tile MFMA GEMM (512 thr, dynamic LDS, dbuf) ----------------
// C[M,N] over A[M,K] * B[N,K]^T, BK=32. TERMS=3: f16 2-plane split (00,01,10).
// TERMS=1: bf16. EPI: 0 fp32, 1 f16-2split*2^-12, 2 bf16.
template<int TERMS, int EPI, int TM, int TN, int WGM, int WGN>
__global__ __launch_bounds__(512, 2)
void gemm_w(const u16* __restrict__ Ab, size_t aBatch, size_t aPlane,
            const u16* __restrict__ Bb, size_t bBatch, size_t bPlane,
            void* __restrict__ Cb, size_t cBatch, size_t cPlane,
            int M, int N, int K)
{
    constexpr int ASZ = TM * 32;                 // u16 per A plane-region
    constexpr int BSZ = TN * 32;
    constexpr int APL = (TERMS == 3) ? 2 : 1;
    constexpr int BUF = APL * (ASZ + BSZ);       // u16 per buffer
    constexpr int FM = TM / WGM / 16;
    constexpr int FN = TN / WGN / 16;
    constexpr int AIT = ASZ / (512 * 8);
    constexpr int BIT = BSZ / (512 * 8);
    extern __shared__ __align__(16) u16 lds[];

    const u16* A = Ab + blockIdx.z * aBatch;
    const u16* B = Bb + blockIdx.z * bBatch;
    const int tid = threadIdx.x;
    const int lane = tid & 63, wave = tid >> 6;
    const int m0 = blockIdx.y * TM, n0 = blockIdx.x * TN;
    const int l15 = lane & 15, q = lane >> 4;
    const int rm = (wave / WGN) * (TM / WGM);
    const int rn = (wave % WGN) * (TN / WGN);

    const int fsw = (q ^ ((l15 >> 1) & 3)) * 8;
    int aoff[FM], boff[FN];
    #pragma unroll
    for (int f = 0; f < FM; ++f) aoff[f] = (rm + f * 16 + l15) * 32 + fsw;
    #pragma unroll
    for (int f = 0; f < FN; ++f) boff[f] = (rn + f * 16 + l15) * 32 + fsw;

    f32x4 acc[FM][FN];
    #pragma unroll
    for (int i = 0; i < FM; ++i)
        #pragma unroll
        for (int j = 0; j < FN; ++j)
            acc[i][j] = (f32x4){0.f, 0.f, 0.f, 0.f};

    auto stage = [&](int pp, int kt) {
        #pragma unroll
        for (int it = 0; it < AIT; ++it) {
            int s = tid + it * 512;
            int r = s >> 2;
            int g = (s & 3) ^ ((r >> 1) & 3);
            int base = pp * BUF + (it * 512 + wave * 64) * 8;
            size_t go = (size_t)(m0 + r) * K + kt + g * 8;
            async16(A + go, &lds[base]);
            if (TERMS == 3) async16(A + aPlane + go, &lds[base + ASZ]);
        }
        #pragma unroll
        for (int it = 0; it < BIT; ++it) {
            int s = tid + it * 512;
            int r = s >> 2;
            int g = (s & 3) ^ ((r >> 1) & 3);
            int base = pp * BUF + APL * ASZ + (it * 512 + wave * 64) * 8;
            size_t go = (size_t)(n0 + r) * K + kt + g * 8;
            async16(B + go, &lds[base]);
            if (TERMS == 3) async16(B + bPlane + go, &lds[base + BSZ]);
        }
    };

    stage(0, 0);
    for (int kt = 0; kt < K; kt += 32) {
        const int p = (kt >> 5) & 1;
        __syncthreads();
        if (kt + 32 < K) stage(p ^ 1, kt + 32);
        const u16* L = &lds[p * BUF];
        if (TERMS == 3) {
            f16x8 a0f[FM], b0f[FN], ax[FM], bx[FN];
            #pragma unroll
            for (int f = 0; f < FM; ++f) a0f[f] = *(const f16x8*)&L[aoff[f]];
            #pragma unroll
            for (int f = 0; f < FN; ++f) b0f[f] = *(const f16x8*)&L[APL * ASZ + boff[f]];
            #pragma unroll
            for (int i = 0; i < FM; ++i)
                #pragma unroll
                for (int j = 0; j < FN; ++j)
                    acc[i][j] = __builtin_amdgcn_mfma_f32_16x16x32_f16(a0f[i], b0f[j], acc[i][j], 0, 0, 0);
            #pragma unroll
            for (int f = 0; f < FN; ++f) bx[f] = *(const f16x8*)&L[APL * ASZ + BSZ + boff[f]];
            #pragma unroll
            for (int i = 0; i < FM; ++i)
                #pragma unroll
                for (int j = 0; j < FN; ++j)
                    acc[i][j] = __builtin_amdgcn_mfma_f32_16x16x32_f16(a0f[i], bx[j], acc[i][j], 0, 0, 0);
            #pragma unroll
            for (int f = 0; f < FM; ++f) ax[f] = *(const f16x8*)&L[ASZ + aoff[f]];
            #pragma unroll
            for (int i = 0; i < FM; ++i)
                #pragma unroll
                for (int j = 0; j < FN; ++j)
                    acc[i][j] = __builtin_amdgcn_mfma_f32_16x16x32_f16(ax[i], b0f[j], acc[i][j], 0, 0, 0);
        } else {
            bf16x8 af[FM], bf_[FN];
            #pragma unroll
            for (int f = 0; f < FM; ++f) af[f] = *(const bf16x8*)&L[aoff[f]];
            #pragma unroll
            for (int f = 0; f < FN; ++f) bf_[f] = *(const bf16x8*)&L[ASZ + boff[f]];
            #pragma unroll
            for (int i = 0; i < FM; ++i)
                #pragma unroll
                for (int j = 0; j < FN; ++j)
                    acc[i][j] = __builtin_amdgcn_mfma_f32_16x16x32_bf16(af[i], bf_[j], acc[i][j], 0, 0, 0);
        }
    }

    #pragma unroll
    for (int i = 0; i < FM; ++i) {
        int row = m0 + rm + i * 16 + q * 4;
        #pragma unroll
        for (int j = 0; j < FN; ++j) {
            int col = n0 + rn + j * 16 + l15;
            #pragma unroll
            for (int r = 0; r < 4; ++r) {
                float v = acc[i][j][r];
                size_t o = (size_t)(row + r) * N + col;
                if (EPI == 0) {
                    ((float*)Cb + blockIdx.z * cBatch)[o] = v;
                } else if (EPI == 1) {
                    u16* C0 = (u16*)Cb + blockIdx.z * cBatch;
                    float vs = v * 0.000244140625f;
                    _Float16 h0 = (_Float16)vs;
                    _Float16 h1 = (_Float16)(vs - (float)h0);
                    C0[o] = __builtin_bit_cast(u16, h0);
                    C0[cPlane + o] = __builtin_bit_cast(u16, h1);
                } else {
                    ((u16*)Cb + blockIdx.z * cBatch)[o] = f2bf(v);
                }
            }
        }
    }
}

// ---------------- row softmax (2048 cols) -> bf16 ----------------
__global__ __launch_bounds__(256)
void softmax_p(const float* __restrict__ Sb, size_t sBatch, u16* __restrict__ Pb, size_t pBatch)
{
    const float* S = Sb + blockIdx.y * sBatch + (size_t)blockIdx.x * 2048;
    u16* P = Pb + blockIdx.y * pBatch + (size_t)blockIdx.x * 2048;
    const int tid = threadIdx.x;

    float4 v0 = *(const float4*)&S[tid * 4];
    float4 v1 = *(const float4*)&S[1024 + tid * 4];

    float m = fmaxf(fmaxf(fmaxf(v0.x, v0.y), fmaxf(v0.z, v0.w)),
                    fmaxf(fmaxf(v1.x, v1.y), fmaxf(v1.z, v1.w)));
    #pragma unroll
    for (int off = 32; off > 0; off >>= 1)
        m = fmaxf(m, __shfl_xor(m, off, 64));
    __shared__ float redm[4];
    if ((tid & 63) == 0) redm[tid >> 6] = m;
    __syncthreads();
    m = fmaxf(fmaxf(redm[0], redm[1]), fmaxf(redm[2], redm[3]));

    v0.x = __expf(v0.x - m); v0.y = __expf(v0.y - m);
    v0.z = __expf(v0.z - m); v0.w = __expf(v0.w - m);
    v1.x = __expf(v1.x - m); v1.y = __expf(v1.y - m);
    v1.z = __expf(v1.z - m); v1.w = __expf(v1.w - m);

    float s = v0.x + v0.y + v0.z + v0.w + v1.x + v1.y + v1.z + v1.w;
    #pragma unroll
    for (int off = 32; off > 0; off >>= 1)
        s += __shfl_xor(s, off, 64);
    __shared__ float reds[4];
    if ((tid & 63) == 0) reds[tid >> 6] = s;
    __syncthreads();
    s = reds[0] + reds[1] + reds[2] + reds[3];

    const float r = 1.0f / s;
    ushort4 o0 = { f2bf(v0.x * r), f2bf(v0.y * r), f2bf(v0.z * r), f2bf(v0.w * r) };
    ushort4 o1 = { f2bf(v1.x * r), f2bf(v1.y * r), f2bf(v1.z * r), f2bf(v1.w * r) };
    *(ushort4*)&P[tid * 4] = o0;
    *(ushort4*)&P[1024 + tid * 4] = o1;
}

// ---------------- driver ----------------
extern "C" void kernel_launch(void* const* d_in, const int* in_sizes, int n_in,
                              void* d_out, int out_size, void* d_ws, size_t ws_size,
                              hipStream_t stream)
{
    const size_t MB = 1048576;
    const size_t WREG = 34 * MB;
    const size_t PER  = 32 * MB;
    const size_t PER_US = PER / 2, PER_F = PER / 4;

    char* ws = (char*)d_ws;
    u16* WQT2 = (u16*)ws;
    u16* WKT2 = (u16*)(ws + 4 * MB);
    u16* M2   = (u16*)(ws + 8 * MB);
    u16* WObf = (u16*)(ws + 12 * MB);
    u16* WVT  = (u16*)(ws + 14 * MB);
    u16* WOV  = (u16*)(ws + 16 * MB);
    u16* xbf  = (u16*)(ws + 18 * MB);

    int G = (ws_size >= WREG + 4 * PER) ? 4 : (ws_size >= WREG + 2 * PER) ? 2 : 1;

    const float* x = (const float*)d_in[0];
    float* out = (float*)d_out;
    dim3 blk(256);

    // opt-in to >64KB dynamic LDS for the wide kernels (idempotent, host-side)
    hipFuncSetAttribute((const void*)gemm_w<3, 0, 256, 256, 2, 4>,
                        hipFuncAttributeMaxDynamicSharedMemorySize, 131072);
    hipFuncSetAttribute((const void*)gemm_w<3, 1, 256, 128, 4, 2>,
                        hipFuncAttributeMaxDynamicSharedMemorySize, 98304);

    // ---- weight prep (once) ----
    tsplit_h2<<<dim3(32, 32, 1), blk, 0, stream>>>((const float*)d_in[1], 0, WQT2, 0, 1048576, 1024, 1024);
    tsplit_h2<<<dim3(32, 32, 1), blk, 0, stream>>>((const float*)d_in[2], 0, WKT2, 0, 1048576, 1024, 1024);
    gemm_big<3, 1><<<dim3(8, 8, 1), blk, 0, stream>>>(WKT2, 0, 1048576, WQT2, 0, 1048576,
                                                      M2, 0, 1048576, 1024, 1024, 1024);
    wcast<<<1024, blk, 0, stream>>>((const float4*)d_in[4], WObf);
    tcast<<<dim3(32, 32, 1), blk, 0, stream>>>((const float*)d_in[3], WVT, 1024, 1024);
    gemm_big<1, 2><<<dim3(8, 8, 1), blk, 0, stream>>>(WObf, 0, 0, WVT, 0, 0,
                                                      WOV, 0, 0, 1024, 1024, 1024);
    wcast<<<8192, blk, 0, stream>>>((const float4*)x, xbf);

    for (int b0 = 0; b0 < 4; b0 += G) {
        char* R = ws + WREG;
        u16*   xT2 = (u16*)R;               // [i,d] 64x f16-split, plane 2097152 u16
        u16*   TT2 = (u16*)(R + 8 * MB);    // [j,d] split(T/64)
        float* S32 = (float*)(R + 16 * MB); // fp32 [i,j]
        u16*   Pb  = (u16*)R;               // bf16 [i,j] (over dead xT2)
        u16*   PTb = (u16*)(R + 8 * MB);    // bf16 [j,i] (over dead TT2)
        u16*   XPT = (u16*)(R + 16 * MB);   // bf16 [j,d'] (over dead S32)

        tsplit_h2<<<dim3(64, 32, G), blk, 0, stream>>>(x + (size_t)b0 * 2097152, 2097152,
                                                       xT2, PER_US, 2097152, 1024, 2048);
        // T^T = (64x)^T M: [j,d] f16-split out
        gemm_w<3, 1, 256, 128, 4, 2><<<dim3(8, 8, G), 512, 98304, stream>>>(
            xT2, PER_US, 2097152, M2, 0, 1048576, TT2, PER_US, 2097152, 2048, 1024, 1024);
        // S[i,j] = (64x)[i,:] . (T/64)[j,:]
        gemm_w<3, 0, 256, 256, 2, 4><<<dim3(8, 8, G), 512, 131072, stream>>>(
            xT2, PER_US, 2097152, TT2, PER_US, 2097152, S32, PER_F, 0, 2048, 2048, 1024);
        softmax_p<<<dim3(2048, G), blk, 0, stream>>>(S32, PER_F, Pb, PER_US);
        tbf16<<<dim3(64, 64, G), blk, 0, stream>>>(Pb, PER_US, PTb, PER_US);
        // XPT[j,d'] = PT[j,:] . xbf[d',:]
        gemm_w<1, 2, 256, 128, 4, 2><<<dim3(8, 8, G), 512, 49152, stream>>>(
            PTb, PER_US, 0, xbf + (size_t)b0 * 2097152, 2097152, 0,
            XPT, PER_US, 0, 2048, 1024, 2048);
        // out[d,j] = WOV[d,:] . XPT[j,:]
        gemm_w<1, 0, 256, 128, 4, 2><<<dim3(16, 4, G), 512, 49152, stream>>>(
            WOV, 0, 0, XPT, PER_US, 0, out + (size_t)b0 * 2097152, 2097152, 0,
            1024, 2048, 1024);
    }
}

// Round 7
// 407.850 us; speedup vs baseline: 8.5649x; 1.0202x over previous
//
#include <hip/hip_runtime.h>
#include <cstddef>
#include <cstdint>

typedef unsigned short u16;
typedef __attribute__((ext_vector_type(8))) short bf16x8;
typedef __attribute__((ext_vector_type(8))) _Float16 f16x8;
typedef __attribute__((ext_vector_type(4))) float f32x4;
typedef __attribute__((ext_vector_type(16))) float f32x16;

#define GLOBAL_AS __attribute__((address_space(1)))
#define LDS_AS __attribute__((address_space(3)))

__device__ __forceinline__ void async16(const u16* g, u16* l) {
    __builtin_amdgcn_global_load_lds((GLOBAL_AS const uint32_t*)g,
                                     (LDS_AS uint32_t*)l, 16, 0, 0);
}

__device__ __forceinline__ u16 f2bf(float f) {
    uint32_t u = __builtin_bit_cast(uint32_t, f);
    uint32_t r = (u + 0x7FFFu + ((u >> 16) & 1u)) >> 16;
    return (u16)r;
}

// ---------------- elementwise prep ----------------
__global__ __launch_bounds__(256)
void wcast(const float4* __restrict__ src, u16* __restrict__ dst)
{
    int i = blockIdx.x * 256 + threadIdx.x;
    float4 v = src[i];
    ushort4 a = { f2bf(v.x), f2bf(v.y), f2bf(v.z), f2bf(v.w) };
    *(ushort4*)&dst[4 * (size_t)i] = a;
}

// transpose + f16 2-split with x64 scale: fp32 [R,C] -> [C,R] planes h0,h1 of 64*v
__global__ __launch_bounds__(256)
void tsplit_h2(const float* __restrict__ Sb, size_t sBatch,
               u16* __restrict__ Db, size_t dBatch, size_t plane,
               int R, int C)
{
    const float* S = Sb + blockIdx.z * sBatch;
    u16* D = Db + blockIdx.z * dBatch;
    __shared__ float t[32][33];
    int tx = threadIdx.x & 31, ty = threadIdx.x >> 5;
    int c0 = blockIdx.x * 32, r0 = blockIdx.y * 32;
    #pragma unroll
    for (int k = 0; k < 4; ++k)
        t[ty + 8 * k][tx] = S[(size_t)(r0 + ty + 8 * k) * C + c0 + tx];
    __syncthreads();
    #pragma unroll
    for (int k = 0; k < 4; ++k) {
        float a = t[tx][ty + 8 * k] * 64.0f;
        _Float16 h0 = (_Float16)a;
        _Float16 h1 = (_Float16)(a - (float)h0);
        size_t o = (size_t)(c0 + ty + 8 * k) * R + r0 + tx;
        D[o] = __builtin_bit_cast(u16, h0);
        D[plane + o] = __builtin_bit_cast(u16, h1);
    }
}

// fused x-prep: fp32 x [1024, 2048] -> bf16 copy [1024,2048] AND transposed
// f16 2-plane x64 split [2048, 1024]
__global__ __launch_bounds__(256)
void xprep(const float* __restrict__ Sb, size_t sBatch,
           u16* __restrict__ BFb, size_t bfBatch,
           u16* __restrict__ Db, size_t dBatch, size_t plane)
{
    const float* S = Sb + blockIdx.z * sBatch;
    u16* BF = BFb + blockIdx.z * bfBatch;
    u16* D = Db + blockIdx.z * dBatch;
    __shared__ float t[32][33];
    int tx = threadIdx.x & 31, ty = threadIdx.x >> 5;
    int c0 = blockIdx.x * 32, r0 = blockIdx.y * 32;
    #pragma unroll
    for (int k = 0; k < 4; ++k) {
        float v = S[(size_t)(r0 + ty + 8 * k) * 2048 + c0 + tx];
        t[ty + 8 * k][tx] = v;
        BF[(size_t)(r0 + ty + 8 * k) * 2048 + c0 + tx] = f2bf(v);
    }
    __syncthreads();
    #pragma unroll
    for (int k = 0; k < 4; ++k) {
        float a = t[tx][ty + 8 * k] * 64.0f;
        _Float16 h0 = (_Float16)a;
        _Float16 h1 = (_Float16)(a - (float)h0);
        size_t o = (size_t)(c0 + ty + 8 * k) * 1024 + r0 + tx;
        D[o] = __builtin_bit_cast(u16, h0);
        D[plane + o] = __builtin_bit_cast(u16, h1);
    }
}

// transpose + cast: fp32 [R,C] -> bf16 [C,R]
__global__ __launch_bounds__(256)
void tcast(const float* __restrict__ S, u16* __restrict__ D, int R, int C)
{
    __shared__ float t[32][33];
    int tx = threadIdx.x & 31, ty = threadIdx.x >> 5;
    int c0 = blockIdx.x * 32, r0 = blockIdx.y * 32;
    #pragma unroll
    for (int k = 0; k < 4; ++k)
        t[ty + 8 * k][tx] = S[(size_t)(r0 + ty + 8 * k) * C + c0 + tx];
    __syncthreads();
    #pragma unroll
    for (int k = 0; k < 4; ++k)
        D[(size_t)(c0 + ty + 8 * k) * R + r0 + tx] = f2bf(t[tx][ty + 8 * k]);
}

// bf16 [2048,2048] transpose
__global__ __launch_bounds__(256)
void tbf16(const u16* __restrict__ Sb, size_t sBatch, u16* __restrict__ Db, size_t dBatch)
{
    const u16* S = Sb + blockIdx.z * sBatch;
    u16* D = Db + blockIdx.z * dBatch;
    __shared__ u16 t[32][34];
    int tx = threadIdx.x & 31, ty = threadIdx.x >> 5;
    int c0 = blockIdx.x * 32, r0 = blockIdx.y * 32;
    #pragma unroll
    for (int k = 0; k < 4; ++k)
        t[ty + 8 * k][tx] = S[(size_t)(r0 + ty + 8 * k) * 2048 + c0 + tx];
    __syncthreads();
    #pragma unroll
    for (int k = 0; k < 4; ++k)
        D[(size_t)(c0 + ty + 8 * k) * 2048 + r0 + tx] = t[tx][ty + 8 * k];
}

// ---------------- 128-tile 16x16 MFMA GEMM (weight prep only, 256 thr) ----------------
#define MMF4(AF, BF)                                                                   \
    _Pragma("unroll") for (int i = 0; i < 4; ++i)                                      \
        _Pragma("unroll") for (int j = 0; j < 4; ++j)                                  \
            acc[i][j] = __builtin_amdgcn_mfma_f32_16x16x32_f16(AF[i], BF[j], acc[i][j], 0, 0, 0);
#define MMB4(AF, BF)                                                                   \
    _Pragma("unroll") for (int i = 0; i < 4; ++i)                                      \
        _Pragma("unroll") for (int j = 0; j < 4; ++j)                                  \
            acc[i][j] = __builtin_amdgcn_mfma_f32_16x16x32_bf16(AF[i], BF[j], acc[i][j], 0, 0, 0);

template<int TERMS, int EPI>
__global__ __launch_bounds__(256)
void gemm_big(const u16* __restrict__ Ab, size_t aBatch, size_t aPlane,
              const u16* __restrict__ Bb, size_t bBatch, size_t bPlane,
              void* __restrict__ Cb, size_t cBatch, size_t cPlane,
              int M, int N, int K)
{
    constexpr int RSZ = 4096;
    constexpr int BUF = (TERMS == 3 ? 4 : 2) * RSZ;
    __shared__ u16 lds[2 * BUF];
    const u16* A = Ab + blockIdx.z * aBatch;
    const u16* B = Bb + blockIdx.z * bBatch;
    const int tid = threadIdx.x;
    const int lane = tid & 63, wave = tid >> 6;
    const int m0 = blockIdx.y * 128, n0 = blockIdx.x * 128;
    const int l15 = lane & 15, q = lane >> 4;
    const int rm = (wave >> 1) * 64, rn = (wave & 1) * 64;

    int sr[2], sg[2], sbase[2];
    #pragma unroll
    for (int it = 0; it < 2; ++it) {
        int s = tid + it * 256;
        sr[it] = s >> 2;
        sg[it] = (s & 3) ^ ((sr[it] >> 1) & 3);
        sbase[it] = (it * 256 + wave * 64) * 8;
    }
    const int fsw = (q ^ ((l15 >> 1) & 3)) * 8;
    int aoff[4], boff[4];
    #pragma unroll
    for (int f = 0; f < 4; ++f) {
        aoff[f] = (rm + f * 16 + l15) * 32 + fsw;
        boff[f] = (rn + f * 16 + l15) * 32 + fsw;
    }

    f32x4 acc[4][4];
    #pragma unroll
    for (int i = 0; i < 4; ++i)
        #pragma unroll
        for (int j = 0; j < 4; ++j)
            acc[i][j] = (f32x4){0.f, 0.f, 0.f, 0.f};

#define STAGEB(PP, KT)                                                                 \
    do {                                                                               \
        _Pragma("unroll")                                                              \
        for (int it = 0; it < 2; ++it) {                                               \
            const size_t ao = (size_t)(m0 + sr[it]) * K + (KT) + sg[it] * 8;           \
            const size_t bo = (size_t)(n0 + sr[it]) * K + (KT) + sg[it] * 8;           \
            const int d = (PP) * BUF + sbase[it];                                      \
            if (TERMS == 3) {                                                          \
                async16(A + ao, &lds[d]);                                              \
                async16(A + aPlane + ao, &lds[d + RSZ]);                               \
                async16(B + bo, &lds[d + 2 * RSZ]);                                    \
                async16(B + bPlane + bo, &lds[d + 3 * RSZ]);                           \
            } else {                                                                   \
                async16(A + ao, &lds[d]);                                              \
                async16(B + bo, &lds[d + RSZ]);                                        \
            }                                                                          \
        }                                                                              \
    } while (0)

    STAGEB(0, 0);
    for (int kt = 0; kt < K; kt += 32) {
        const int p = (kt >> 5) & 1;
        __syncthreads();
        if (kt + 32 < K) STAGEB(p ^ 1, kt + 32);
        const u16* L = &lds[p * BUF];
        if (TERMS == 3) {
            f16x8 a0f[4], b0f[4], xf[4];
            #pragma unroll
            for (int f = 0; f < 4; ++f) a0f[f] = *(const f16x8*)&L[aoff[f]];
            #pragma unroll
            for (int f = 0; f < 4; ++f) b0f[f] = *(const f16x8*)&L[2 * RSZ + boff[f]];
            MMF4(a0f, b0f);
            #pragma unroll
            for (int f = 0; f < 4; ++f) xf[f] = *(const f16x8*)&L[3 * RSZ + boff[f]];
            MMF4(a0f, xf);
            #pragma unroll
            for (int f = 0; f < 4; ++f) xf[f] = *(const f16x8*)&L[RSZ + aoff[f]];
            MMF4(xf, b0f);
        } else {
            bf16x8 af[4], bf_[4];
            #pragma unroll
            for (int f = 0; f < 4; ++f) af[f] = *(const bf16x8*)&L[aoff[f]];
            #pragma unroll
            for (int f = 0; f < 4; ++f) bf_[f] = *(const bf16x8*)&L[RSZ + boff[f]];
            MMB4(af, bf_);
        }
    }
#undef STAGEB

    #pragma unroll
    for (int i = 0; i < 4; ++i) {
        int row = m0 + rm + i * 16 + q * 4;
        #pragma unroll
        for (int j = 0; j < 4; ++j) {
            int col = n0 + rn + j * 16 + l15;
            #pragma unroll
            for (int r = 0; r < 4; ++r) {
                float v = acc[i][j][r];
                size_t o = (size_t)(row + r) * N + col;
                if (EPI == 0) {
                    ((float*)Cb + blockIdx.z * cBatch)[o] = v;
                } else if (EPI == 1) {
                    u16* C0 = (u16*)Cb + blockIdx.z * cBatch;
                    float vs = v * 0.000244140625f;
                    _Float16 h0 = (_Float16)vs;
                    _Float16 h1 = (_Float16)(vs - (float)h0);
                    C0[o] = __builtin_bit_cast(u16, h0);
                    C0[cPlane + o] = __builtin_bit_cast(u16, h1);
                } else {
                    ((u16*)Cb + blockIdx.z * cBatch)[o] = f2bf(v);
                }
            }
        }
    }
}

// ---------------- wide-tile 32x32x16 MFMA GEMM (512 thr, dyn LDS, dbuf) ----------------
// C[M,N] over A[M,K] * B[N,K]^T, BK=32. TERMS=3: f16 2-plane split (00,01,10).
// TERMS=1: bf16. EPI: 0 fp32, 1 f16-2split*2^-12, 2 bf16.
// 32x32x16 layouts: A[m=lane&31][k=(lane>>5)*8+j]; C: col=lane&31,
// row=(reg&3)+8*(reg>>2)+4*(lane>>5)  [HW-verified m74/m101].
template<int TERMS, int EPI, int TM, int TN, int WGM, int WGN>
__global__ __launch_bounds__(512, 2)
void gemm_w(const u16* __restrict__ Ab, size_t aBatch, size_t aPlane,
            const u16* __restrict__ Bb, size_t bBatch, size_t bPlane,
            void* __restrict__ Cb, size_t cBatch, size_t cPlane,
            int M, int N, int K)
{
    constexpr int ASZ = TM * 32;
    constexpr int BSZ = TN * 32;
    constexpr int APL = (TERMS == 3) ? 2 : 1;
    constexpr int BUF = APL * (ASZ + BSZ);
    constexpr int FM = TM / WGM / 32;
    constexpr int FN = TN / WGN / 32;
    constexpr int AIT = TM / 128;
    constexpr int BIT = TN / 128;
    extern __shared__ __align__(16) u16 lds[];

    // XCD cluster swizzle: 4x2 block clusters land on one XCD (requires gx%4==0, gy%2==0)
    int bid = blockIdx.x + gridDim.x * blockIdx.y;
    int cpr = gridDim.x >> 2;
    int c8 = bid & 7, kk = bid >> 3;
    int bx = (kk % cpr) * 4 + (c8 & 3);
    int by = (kk / cpr) * 2 + (c8 >> 2);

    const u16* A = Ab + blockIdx.z * aBatch;
    const u16* B = Bb + blockIdx.z * bBatch;
    const int tid = threadIdx.x;
    const int lane = tid & 63, wave = tid >> 6;
    const int m0 = by * TM, n0 = bx * TN;
    const int l31 = lane & 31, half = lane >> 5;
    const int rm = (wave / WGN) * (TM / WGM);
    const int rn = (wave % WGN) * (TN / WGN);

    int arow[FM], asw[FM], brow[FN], bsw[FN];
    #pragma unroll
    for (int f = 0; f < FM; ++f) { arow[f] = rm + f * 32 + l31; asw[f] = (arow[f] >> 1) & 3; }
    #pragma unroll
    for (int f = 0; f < FN; ++f) { brow[f] = rn + f * 32 + l31; bsw[f] = (brow[f] >> 1) & 3; }

    f32x16 acc[FM][FN];
    #pragma unroll
    for (int i = 0; i < FM; ++i)
        #pragma unroll
        for (int j = 0; j < FN; ++j)
            #pragma unroll
            for (int r = 0; r < 16; ++r) acc[i][j][r] = 0.f;

    auto stage = [&](int pp, int kt) {
        #pragma unroll
        for (int it = 0; it < AIT; ++it) {
            int s = tid + it * 512;
            int r = s >> 2;
            int g = (s & 3) ^ ((r >> 1) & 3);
            int base = pp * BUF + (it * 512 + wave * 64) * 8;
            size_t go = (size_t)(m0 + r) * K + kt + g * 8;
            async16(A + go, &lds[base]);
            if (TERMS == 3) async16(A + aPlane + go, &lds[base + ASZ]);
        }
        #pragma unroll
        for (int it = 0; it < BIT; ++it) {
            int s = tid + it * 512;
            int r = s >> 2;
            int g = (s & 3) ^ ((r >> 1) & 3);
            int base = pp * BUF + APL * ASZ + (it * 512 + wave * 64) * 8;
            size_t go = (size_t)(n0 + r) * K + kt + g * 8;
            async16(B + go, &lds[base]);
            if (TERMS == 3) async16(B + bPlane + go, &lds[base + BSZ]);
        }
    };

    stage(0, 0);
    for (int kt = 0; kt < K; kt += 32) {
        const int p = (kt >> 5) & 1;
        __syncthreads();
        if (kt + 32 < K) stage(p ^ 1, kt + 32);
        const u16* L = &lds[p * BUF];
        #pragma unroll
        for (int h = 0; h < 2; ++h) {
            if (TERMS == 3) {
                f16x8 a0[FM], b0[FN], tx[FM > FN ? FM : FN];
                #pragma unroll
                for (int f = 0; f < FM; ++f)
                    a0[f] = *(const f16x8*)&L[arow[f] * 32 + ((2 * h + half) ^ asw[f]) * 8];
                #pragma unroll
                for (int f = 0; f < FN; ++f)
                    b0[f] = *(const f16x8*)&L[APL * ASZ + brow[f] * 32 + ((2 * h + half) ^ bsw[f]) * 8];
                #pragma unroll
                for (int i = 0; i < FM; ++i)
                    #pragma unroll
                    for (int j = 0; j < FN; ++j)
                        acc[i][j] = __builtin_amdgcn_mfma_f32_32x32x16_f16(a0[i], b0[j], acc[i][j], 0, 0, 0);
                #pragma unroll
                for (int f = 0; f < FN; ++f)
                    tx[f] = *(const f16x8*)&L[APL * ASZ + BSZ + brow[f] * 32 + ((2 * h + half) ^ bsw[f]) * 8];
                #pragma unroll
                for (int i = 0; i < FM; ++i)
                    #pragma unroll
                    for (int j = 0; j < FN; ++j)
                        acc[i][j] = __builtin_amdgcn_mfma_f32_32x32x16_f16(a0[i], tx[j], acc[i][j], 0, 0, 0);
                #pragma unroll
                for (int f = 0; f < FM; ++f)
                    tx[f] = *(const f16x8*)&L[ASZ + arow[f] * 32 + ((2 * h + half) ^ asw[f]) * 8];
                #pragma unroll
                for (int i = 0; i < FM; ++i)
                    #pragma unroll
                    for (int j = 0; j < FN; ++j)
                        acc[i][j] = __builtin_amdgcn_mfma_f32_32x32x16_f16(tx[i], b0[j], acc[i][j], 0, 0, 0);
            } else {
                bf16x8 a0[FM], b0[FN];
                #pragma unroll
                for (int f = 0; f < FM; ++f)
                    a0[f] = *(const bf16x8*)&L[arow[f] * 32 + ((2 * h + half) ^ asw[f]) * 8];
                #pragma unroll
                for (int f = 0; f < FN; ++f)
                    b0[f] = *(const bf16x8*)&L[ASZ + brow[f] * 32 + ((2 * h + half) ^ bsw[f]) * 8];
                #pragma unroll
                for (int i = 0; i < FM; ++i)
                    #pragma unroll
                    for (int j = 0; j < FN; ++j)
                        acc[i][j] = __builtin_amdgcn_mfma_f32_32x32x16_bf16(a0[i], b0[j], acc[i][j], 0, 0, 0);
            }
        }
    }

    #pragma unroll
    for (int i = 0; i < FM; ++i) {
        #pragma unroll
        for (int j = 0; j < FN; ++j) {
            int col = n0 + rn + j * 32 + l31;
            #pragma unroll
            for (int r = 0; r < 16; ++r) {
                int row = m0 + rm + i * 32 + (r & 3) + 8 * (r >> 2) + 4 * half;
                float v = acc[i][j][r];
                size_t o = (size_t)row * N + col;
                if (EPI == 0) {
                    ((float*)Cb + blockIdx.z * cBatch)[o] = v;
                } else if (EPI == 1) {
                    u16* C0 = (u16*)Cb + blockIdx.z * cBatch;
                    float vs = v * 0.000244140625f;
                    _Float16 h0 = (_Float16)vs;
                    _Float16 h1 = (_Float16)(vs - (float)h0);
                    C0[o] = __builtin_bit_cast(u16, h0);
                    C0[cPlane + o] = __builtin_bit_cast(u16, h1);
                } else {
                    ((u16*)Cb + blockIdx.z * cBatch)[o] = f2bf(v);
                }
            }
        }
    }
}

// ---------------- row softmax (2048 cols) -> bf16 ----------------
__global__ __launch_bounds__(256)
void softmax_p(const float* __restrict__ Sb, size_t sBatch, u16* __restrict__ Pb, size_t pBatch)
{
    const float* S = Sb + blockIdx.y * sBatch + (size_t)blockIdx.x * 2048;
    u16* P = Pb + blockIdx.y * pBatch + (size_t)blockIdx.x * 2048;
    const int tid = threadIdx.x;

    float4 v0 = *(const float4*)&S[tid * 4];
    float4 v1 = *(const float4*)&S[1024 + tid * 4];

    float m = fmaxf(fmaxf(fmaxf(v0.x, v0.y), fmaxf(v0.z, v0.w)),
                    fmaxf(fmaxf(v1.x, v1.y), fmaxf(v1.z, v1.w)));
    #pragma unroll
    for (int off = 32; off > 0; off >>= 1)
        m = fmaxf(m, __shfl_xor(m, off, 64));
    __shared__ float redm[4];
    if ((tid & 63) == 0) redm[tid >> 6] = m;
    __syncthreads();
    m = fmaxf(fmaxf(redm[0], redm[1]), fmaxf(redm[2], redm[3]));

    v0.x = __expf(v0.x - m); v0.y = __expf(v0.y - m);
    v0.z = __expf(v0.z - m); v0.w = __expf(v0.w - m);
    v1.x = __expf(v1.x - m); v1.y = __expf(v1.y - m);
    v1.z = __expf(v1.z - m); v1.w = __expf(v1.w - m);

    float s = v0.x + v0.y + v0.z + v0.w + v1.x + v1.y + v1.z + v1.w;
    #pragma unroll
    for (int off = 32; off > 0; off >>= 1)
        s += __shfl_xor(s, off, 64);
    __shared__ float reds[4];
    if ((tid & 63) == 0) reds[tid >> 6] = s;
    __syncthreads();
    s = reds[0] + reds[1] + reds[2] + reds[3];

    const float r = 1.0f / s;
    ushort4 o0 = { f2bf(v0.x * r), f2bf(v0.y * r), f2bf(v0.z * r), f2bf(v0.w * r) };
    ushort4 o1 = { f2bf(v1.x * r), f2bf(v1.y * r), f2bf(v1.z * r), f2bf(v1.w * r) };
    *(ushort4*)&P[tid * 4] = o0;
    *(ushort4*)&P[1024 + tid * 4] = o1;
}

// ---------------- driver ----------------
extern "C" void kernel_launch(void* const* d_in, const int* in_sizes, int n_in,
                              void* d_out, int out_size, void* d_ws, size_t ws_size,
                              hipStream_t stream)
{
    const size_t MB = 1048576;
    const size_t WREG = 34 * MB;
    const size_t PER  = 32 * MB;
    const size_t PER_US = PER / 2, PER_F = PER / 4;

    char* ws = (char*)d_ws;
    u16* WQT2 = (u16*)ws;
    u16* WKT2 = (u16*)(ws + 4 * MB);
    u16* M2   = (u16*)(ws + 8 * MB);
    u16* WObf = (u16*)(ws + 12 * MB);
    u16* WVT  = (u16*)(ws + 14 * MB);
    u16* WOV  = (u16*)(ws + 16 * MB);
    u16* xbf  = (u16*)(ws + 18 * MB);

    int G = (ws_size >= WREG + 4 * PER) ? 4 : (ws_size >= WREG + 2 * PER) ? 2 : 1;

    const float* x = (const float*)d_in[0];
    float* out = (float*)d_out;
    dim3 blk(256);

    hipFuncSetAttribute((const void*)gemm_w<3, 0, 256, 256, 2, 4>,
                        hipFuncAttributeMaxDynamicSharedMemorySize, 131072);
    hipFuncSetAttribute((const void*)gemm_w<3, 1, 256, 128, 4, 2>,
                        hipFuncAttributeMaxDynamicSharedMemorySize, 98304);

    // ---- weight prep (once) ----
    tsplit_h2<<<dim3(32, 32, 1), blk, 0, stream>>>((const float*)d_in[1], 0, WQT2, 0, 1048576, 1024, 1024);
    tsplit_h2<<<dim3(32, 32, 1), blk, 0, stream>>>((const float*)d_in[2], 0, WKT2, 0, 1048576, 1024, 1024);
    gemm_big<3, 1><<<dim3(8, 8, 1), blk, 0, stream>>>(WKT2, 0, 1048576, WQT2, 0, 1048576,
                                                      M2, 0, 1048576, 1024, 1024, 1024);
    wcast<<<1024, blk, 0, stream>>>((const float4*)d_in[4], WObf);
    tcast<<<dim3(32, 32, 1), blk, 0, stream>>>((const float*)d_in[3], WVT, 1024, 1024);
    gemm_big<1, 2><<<dim3(8, 8, 1), blk, 0, stream>>>(WObf, 0, 0, WVT, 0, 0,
                                                      WOV, 0, 0, 1024, 1024, 1024);

    for (int b0 = 0; b0 < 4; b0 += G) {
        char* R = ws + WREG;
        u16*   xT2 = (u16*)R;               // [i,d] 64x f16-split, plane 2097152 u16
        u16*   TT2 = (u16*)(R + 8 * MB);    // [j,d] split(T/64)
        float* S32 = (float*)(R + 16 * MB); // fp32 [i,j]
        u16*   Pb  = (u16*)R;               // bf16 [i,j] (over dead xT2)
        u16*   PTb = (u16*)(R + 8 * MB);    // bf16 [j,i] (over dead TT2)
        u16*   XPT = (u16*)(R + 16 * MB);   // bf16 [j,d'] (over dead S32)

        // x -> xbf (bf16 copy) + xT2 (transposed 64x f16 2-plane), one pass
        xprep<<<dim3(64, 32, G), blk, 0, stream>>>(x + (size_t)b0 * 2097152, 2097152,
                                                   xbf + (size_t)b0 * 2097152, 2097152,
                                                   xT2, PER_US, 2097152);
        // T^T = (64x)^T M: [j,d] f16-split out
        gemm_w<3, 1, 256, 128, 4, 2><<<dim3(8, 8, G), 512, 98304, stream>>>(
            xT2, PER_US, 2097152, M2, 0, 1048576, TT2, PER_US, 2097152, 2048, 1024, 1024);
        // S[i,j] = (64x)[i,:] . (T/64)[j,:]
        gemm_w<3, 0, 256, 256, 2, 4><<<dim3(8, 8, G), 512, 131072, stream>>>(
            xT2, PER_US, 2097152, TT2, PER_US, 2097152, S32, PER_F, 0, 2048, 2048, 1024);
        softmax_p<<<dim3(2048, G), blk, 0, stream>>>(S32, PER_F, Pb, PER_US);
        tbf16<<<dim3(64, 64, G), blk, 0, stream>>>(Pb, PER_US, PTb, PER_US);
        // XPT[j,d'] = PT[j,:] . xbf[d',:]
        gemm_w<1, 2, 256, 128, 4, 2><<<dim3(8, 8, G), 512, 49152, stream>>>(
            PTb, PER_US, 0, xbf + (size_t)b0 * 2097152, 2097152, 0,
            XPT, PER_US, 0, 2048, 1024, 2048);
        // out[d,j] = WOV[d,:] . XPT[j,:]
        gemm_w<1, 0, 256, 128, 4, 2><<<dim3(16, 4, G), 512, 49152, stream>>>(
            WOV, 0, 0, XPT, PER_US, 0, out + (size_t)b0 * 2097152, 2097152, 0,
            1024, 2048, 1024);
    }
}